// Round 2
// baseline (534.645 us; speedup 1.0000x reference)
//
#include <hip/hip_runtime.h>
#include <math.h>

#define BATCH 4
#define CIN   1024
#define CB    256
#define HH    64
#define WW    64
#define PP    4096          // HH*WW
#define EPSV  1e-5f

using shortx8 = __attribute__((ext_vector_type(8))) short;
using floatx4 = __attribute__((ext_vector_type(4))) float;
using intx4   = __attribute__((ext_vector_type(4))) int;

static __device__ inline unsigned short f2bf(float f) {
    unsigned int u = __float_as_uint(f);
    u += 0x7fffu + ((u >> 16) & 1u);      // RNE
    return (unsigned short)(u >> 16);
}
static __device__ inline float bf2f(unsigned short s) {
    return __uint_as_float(((unsigned int)s) << 16);
}

// ---------------------------------------------------------------------------
// bf16 MFMA GEMM (conv1 / conv3). Unchanged from R4 (proven).
// ---------------------------------------------------------------------------
__global__ __launch_bounds__(256)
void gemm_bf16(const unsigned short* __restrict__ A,
               const unsigned short* __restrict__ BTg,
               float* __restrict__ Cg, int M, int N, int K) {
    const int b = blockIdx.z;
    const unsigned short* BT = BTg + (size_t)b * N * K;
    float* C = Cg + (size_t)b * M * N;
    const int m0 = blockIdx.y * 128;
    const int n0 = blockIdx.x * 128;
    const int tid = threadIdx.x;
    const int lane = tid & 63;
    const int wid = tid >> 6;
    const int l15 = lane & 15;
    const int quad = lane >> 4;

    __shared__ __align__(16) unsigned short As[128 * 40];
    __shared__ __align__(16) unsigned short Bs[128 * 40];

    floatx4 acc[2][8];
#pragma unroll
    for (int i = 0; i < 2; i++)
#pragma unroll
        for (int j = 0; j < 8; j++) acc[i][j] = (floatx4){0.f, 0.f, 0.f, 0.f};

    const int row = tid >> 1;
    const int half = tid & 1;

    for (int k0 = 0; k0 < K; k0 += 32) {
        const unsigned short* ga = A + (size_t)(m0 + row) * K + k0 + half * 16;
        const unsigned short* gb = BT + (size_t)(n0 + row) * K + k0 + half * 16;
        float4 a0 = *(const float4*)ga;
        float4 a1 = *(const float4*)(ga + 8);
        float4 b0 = *(const float4*)gb;
        float4 b1 = *(const float4*)(gb + 8);
        __syncthreads();
        *(float4*)((char*)As + row * 80 + half * 32) = a0;
        *(float4*)((char*)As + row * 80 + half * 32 + 16) = a1;
        *(float4*)((char*)Bs + row * 80 + half * 32) = b0;
        *(float4*)((char*)Bs + row * 80 + half * 32 + 16) = b1;
        __syncthreads();
        shortx8 af[2], bf[8];
#pragma unroll
        for (int i = 0; i < 2; i++)
            af[i] = *(const shortx8*)((const char*)As +
                    (wid * 32 + 16 * i + l15) * 80 + quad * 16);
#pragma unroll
        for (int j = 0; j < 8; j++)
            bf[j] = *(const shortx8*)((const char*)Bs +
                    (16 * j + l15) * 80 + quad * 16);
#pragma unroll
        for (int i = 0; i < 2; i++)
#pragma unroll
            for (int j = 0; j < 8; j++)
                acc[i][j] = __builtin_amdgcn_mfma_f32_16x16x32_bf16(
                    af[i], bf[j], acc[i][j], 0, 0, 0);
    }

#pragma unroll
    for (int i = 0; i < 2; i++) {
#pragma unroll
        for (int r = 0; r < 4; r++) {
            int m = m0 + wid * 32 + 16 * i + quad * 4 + r;
            float* dst = C + (size_t)m * N + n0 + l15;
#pragma unroll
            for (int j = 0; j < 8; j++)
                dst[16 * j] = acc[i][j][r];
        }
    }
}

// ---------------------------------------------------------------------------
// Tiled transpose + fp32->bf16: src [b][C][P] -> dst [b][P][C]
// ---------------------------------------------------------------------------
__global__ __launch_bounds__(256)
void transp_bf16(const float* __restrict__ src, unsigned short* __restrict__ dst,
                 int C, int P) {
    const int p0 = blockIdx.x * 64;
    const int c0 = blockIdx.y * 64;
    const int b = blockIdx.z;
    __shared__ unsigned short t[64][72];
    const float* s = src + ((size_t)b * C + c0) * P + p0;
    for (int e = threadIdx.x; e < 4096; e += 256) {
        int r = e >> 6, col = e & 63;
        t[r][col] = f2bf(s[(size_t)r * P + col]);
    }
    __syncthreads();
    unsigned short* d = dst + ((size_t)b * P + p0) * C + c0;
    for (int u = threadIdx.x; u < 512; u += 256) {
        int pr = u >> 3, c8 = (u & 7) * 8;
        ushort4 v0, v1;
        v0.x = t[c8 + 0][pr]; v0.y = t[c8 + 1][pr];
        v0.z = t[c8 + 2][pr]; v0.w = t[c8 + 3][pr];
        v1.x = t[c8 + 4][pr]; v1.y = t[c8 + 5][pr];
        v1.z = t[c8 + 6][pr]; v1.w = t[c8 + 7][pr];
        *(ushort4*)&d[(size_t)pr * C + c8] = v0;
        *(ushort4*)&d[(size_t)pr * C + c8 + 4] = v1;
    }
}

// ---------------------------------------------------------------------------
// GN2 apply + ReLU + transpose-convert: out2 fp32 [b][256][P] -> bf16 [b][P][256]
// ---------------------------------------------------------------------------
__global__ __launch_bounds__(256)
void gn2t(const float* __restrict__ src, const float2* __restrict__ st,
          const float* __restrict__ sc, const float* __restrict__ bi,
          unsigned short* __restrict__ dst) {
    const int p0 = blockIdx.x * 64;
    const int c0 = blockIdx.y * 64;
    const int b = blockIdx.z;
    __shared__ unsigned short t[64][72];
    const float* s = src + ((size_t)b * CB + c0) * PP + p0;
    for (int e = threadIdx.x; e < 4096; e += 256) {
        int r = e >> 6, col = e & 63;
        int c = c0 + r;
        float2 m = st[b * 32 + (c >> 3)];       // Cpg = 8
        float a = m.y * sc[c];
        float bb = bi[c] - m.x * a;
        t[r][col] = f2bf(fmaxf(s[(size_t)r * PP + col] * a + bb, 0.f));
    }
    __syncthreads();
    unsigned short* d = dst + ((size_t)b * PP + p0) * CB + c0;
    for (int u = threadIdx.x; u < 512; u += 256) {
        int pr = u >> 3, c8 = (u & 7) * 8;
        ushort4 v0, v1;
        v0.x = t[c8 + 0][pr]; v0.y = t[c8 + 1][pr];
        v0.z = t[c8 + 2][pr]; v0.w = t[c8 + 3][pr];
        v1.x = t[c8 + 4][pr]; v1.y = t[c8 + 5][pr];
        v1.z = t[c8 + 6][pr]; v1.w = t[c8 + 7][pr];
        *(ushort4*)&d[(size_t)pr * CB + c8] = v0;
        *(ushort4*)&d[(size_t)pr * CB + c8 + 4] = v1;
    }
}

// ---------------------------------------------------------------------------
__global__ __launch_bounds__(256)
void cvt_bf16(const float* __restrict__ s, unsigned short* __restrict__ d, int n) {
    int i = blockIdx.x * 256 + threadIdx.x;
    if (i < n) d[i] = f2bf(s[i]);
}

// ---------------------------------------------------------------------------
__global__ __launch_bounds__(256)
void gn_stats(const float* __restrict__ src, float2* __restrict__ stats,
              int C, int Cpg) {
    int bg = blockIdx.x;
    int b = bg >> 5, g = bg & 31;
    const float* base = src + ((size_t)b * C + (size_t)g * Cpg) * PP;
    int cnt = Cpg * PP;
    float s = 0.f, ss = 0.f;
    const float4* p4 = (const float4*)base;
    int n4 = cnt >> 2;
    for (int i = threadIdx.x; i < n4; i += 256) {
        float4 v = p4[i];
        s += v.x + v.y + v.z + v.w;
        ss += v.x * v.x + v.y * v.y + v.z * v.z + v.w * v.w;
    }
    for (int off = 32; off > 0; off >>= 1) {
        s += __shfl_down(s, off, 64);
        ss += __shfl_down(ss, off, 64);
    }
    __shared__ float rs[4], rss[4];
    int lane = threadIdx.x & 63, wid = threadIdx.x >> 6;
    if (lane == 0) { rs[wid] = s; rss[wid] = ss; }
    __syncthreads();
    if (threadIdx.x == 0) {
        float S = rs[0] + rs[1] + rs[2] + rs[3];
        float SS = rss[0] + rss[1] + rss[2] + rss[3];
        float mean = S / (float)cnt;
        float var = SS / (float)cnt - mean * mean;
        stats[bg] = make_float2(mean, rsqrtf(var + EPSV));
    }
}

// ---------------------------------------------------------------------------
// GN1 apply + ReLU, fp32 in -> bf16 out (bfA). C=256, Cpg=8 hardcoded.
// ---------------------------------------------------------------------------
__global__ __launch_bounds__(256)
void gn1_apply_bf(const float* __restrict__ src, const float2* __restrict__ stats,
                  const float* __restrict__ sc, const float* __restrict__ bi,
                  unsigned short* __restrict__ dst) {
    long i = (long)blockIdx.x * 256 + threadIdx.x;
    long total4 = ((long)BATCH * CB * PP) >> 2;
    if (i >= total4) return;
    long e = i << 2;
    int c = (int)((e >> 12) & 255);
    int b = (int)(e >> 20);
    float2 st = stats[b * 32 + (c >> 3)];
    float a = st.y * sc[c];
    float bb = bi[c] - st.x * a;
    float4 v = ((const float4*)src)[i];
    ushort4 o;
    o.x = f2bf(fmaxf(v.x * a + bb, 0.f));
    o.y = f2bf(fmaxf(v.y * a + bb, 0.f));
    o.z = f2bf(fmaxf(v.z * a + bb, 0.f));
    o.w = f2bf(fmaxf(v.w * a + bb, 0.f));
    ((ushort4*)dst)[i] = o;
}

// ---------------------------------------------------------------------------
// bfB[m] = bfA[m+1] (flat shift; boundary dwords never used by gathers).
// ---------------------------------------------------------------------------
__global__ __launch_bounds__(256)
void mk_shift(const unsigned short* __restrict__ a, unsigned short* __restrict__ bsh) {
    int t = blockIdx.x * 256 + threadIdx.x;
    uint2 d01 = ((const uint2*)a)[t];
    unsigned int d2 = ((const unsigned int*)a)[2 * t + 2];
    unsigned int w0 = (d01.x >> 16) | (d01.y << 16);
    unsigned int w1 = (d01.y >> 16) | (d2 << 16);
    ((uint2*)bsh)[t] = make_uint2(w0, w1);
}

// ---------------------------------------------------------------------------
__global__ __launch_bounds__(256)
void om_init(float* __restrict__ om, const float* __restrict__ boff) {
    int t = blockIdx.x * 256 + threadIdx.x;
    if (t < BATCH * 27 * PP) {
        int r = (t >> 12) % 27;
        om[t] = boff[r];
    }
}

// ---------------------------------------------------------------------------
// 3x3 offset conv (R8 version: 8-channel strip staging, 8 barriers total).
// ---------------------------------------------------------------------------
__global__ __launch_bounds__(256)
void conv_off_k(const unsigned short* __restrict__ o1bf, const float* __restrict__ w_off,
                float* __restrict__ om) {
    const int y0 = blockIdx.x * 4;
    const int c0 = blockIdx.y * 32;
    const int b = blockIdx.z;
    const int tid = threadIdx.x;
    const int tx = tid & 63, ty = tid >> 6;

    __shared__ __align__(16) float Aall[32 * 384];   // 48 KB
    __shared__ float strip[8 * 384];                 // 12 KB

    for (int e = tid; e < 32 * 384; e += 256) {
        int c = e / 384;
        int rk = e % 384;
        int r = rk / 12, k = rk % 12;
        float v = 0.f;
        if (r < 27 && k < 9) v = w_off[((size_t)r * CB + (c0 + c)) * 9 + k];
        Aall[e] = v;
    }

    float acc[8][4];
#pragma unroll
    for (int i = 0; i < 8; i++)
#pragma unroll
        for (int j = 0; j < 4; j++) acc[i][j] = 0.f;

    for (int cg = 0; cg < 4; cg++) {
        __syncthreads();
        for (int e = tid; e < 8 * 384; e += 256) {
            int c = e / 384, rk = e % 384;
            int r = rk >> 6, col = rk & 63;
            int gy = y0 + r - 1;
            strip[e] = (gy >= 0 && gy < 64)
                ? bf2f(o1bf[(((size_t)b * CB + c0 + cg * 8 + c) << 12) + (gy << 6) + col])
                : 0.f;
        }
        __syncthreads();
        for (int c = 0; c < 8; c++) {
            float v[6][3];
#pragma unroll
            for (int r = 0; r < 6; r++)
#pragma unroll
                for (int d = 0; d < 3; d++) {
                    int col = tx + d - 1;
                    v[r][d] = (col >= 0 && col < 64) ? strip[c * 384 + r * 64 + col] : 0.f;
                }
            const float* Ac = &Aall[(cg * 8 + c) * 384];
#pragma unroll
            for (int i = 0; i < 8; i++) {
                int m = ty + 4 * i;
                float4 w0 = *(const float4*)(Ac + m * 12);
                float4 w1v = *(const float4*)(Ac + m * 12 + 4);
                float w8 = Ac[m * 12 + 8];
                float wk[9] = {w0.x, w0.y, w0.z, w0.w, w1v.x, w1v.y, w1v.z, w1v.w, w8};
#pragma unroll
                for (int kk = 0; kk < 9; kk++) {
                    int dy = kk / 3, dx = kk % 3;
#pragma unroll
                    for (int j = 0; j < 4; j++)
                        acc[i][j] += wk[kk] * v[j + dy][dx];
                }
            }
        }
    }
#pragma unroll
    for (int i = 0; i < 8; i++) {
        int m = ty + 4 * i;
        if (m < 27) {
#pragma unroll
            for (int j = 0; j < 4; j++) {
                int p = ((y0 + j) << 6) + tx;
                atomicAdd(&om[((size_t)b * 27 + m) * PP + p], acc[i][j]);
            }
        }
    }
}

// ---------------------------------------------------------------------------
// w2 fp32 [o][c][tap] -> bf16, K reordered: w2bf[o][tap*256 + c]
// ---------------------------------------------------------------------------
__global__ __launch_bounds__(256)
void w2conv(const float* __restrict__ w2, unsigned short* __restrict__ w2bf) {
    int t = blockIdx.x * 256 + threadIdx.x;
    if (t >= 256 * 2304) return;
    int o = t / 2304;
    int r = t - o * 2304;
    int tap = r >> 8, c = r & 255;
    w2bf[t] = f2bf(w2[((size_t)o * 256 + c) * 9 + tap]);
}

// ---------------------------------------------------------------------------
// Deformable einsum, bf16 MFMA. R12: back to the proven R10 two-barrier body,
// but pixel tile 32 -> 16: grid 512 -> 1024 blocks (4 blocks/CU, 2048 thr/CU
// = thread-limit occupancy). R10/R11 post-mortem: the kernel is latency/
// barrier-bound and GRID-LIMITED (512 blocks = 2/CU caps occupancy at 39%);
// TLP (other resident blocks running while one drains its gathers at the
// barrier) is the structural fix, not ILP. Pixel-split duplicates no gather
// traffic (pixels partition); only L2-resident w2bf A-reads double.
// Kept from R11: SoA sampling tables (bank conflicts 1.12e7 -> 4.2e6).
// Dropped from R11: direct-A loads, light barriers, setprio (all regressed).
// Per (cc,tap) iter: each thread builds ONE B value (2 gather dwords),
// each wave does 2 MFMAs (N=16).
// ---------------------------------------------------------------------------
__global__ __launch_bounds__(512, 8)
void gemm2_mfma(const unsigned short* __restrict__ bfA,
                const unsigned short* __restrict__ bfB,
                const unsigned short* __restrict__ w2bf,
                const float* __restrict__ om, float* __restrict__ out2) {
    const int blk = blockIdx.x;
    const int xcd = blk & 7;
    const int b = xcd >> 1;                          // batch per XCD-pair
    const int p0 = (((blk >> 3) << 1) | (xcd & 1)) * 16;
    const int tid = threadIdx.x;
    const int lane = tid & 63;
    const int wid = tid >> 6;          // 0..7
    const int l15 = lane & 15;
    const int quad = lane >> 4;        // 0..3

    __shared__ __align__(16) unsigned short As[256 * 40];   // 20 KB
    __shared__ __align__(16) unsigned short Bs[16 * 40];    // 1.25 KB
    __shared__ float sw0[144], sw1[144], sw2[144], sw3[144]; // SoA tables
    __shared__ int   si0[144], si1[144];

    // sampling tables (same math as R10, SoA layout), 9 taps x 16 pixels
    const float* ob = om + (size_t)b * 27 * PP;
    for (int e = tid; e < 144; e += 512) {
        int k = e >> 4, p = e & 15;
        int pg = p0 + p;
        float offx = ob[(size_t)k * PP + pg];
        float offy = ob[(size_t)(9 + k) * PP + pg];
        float ms = 1.f / (1.f + expf(-ob[(size_t)(18 + k) * PP + pg]));
        int y = pg >> 6, x = pg & 63;
        float py = (float)(y + k / 3 - 1) + offy;
        float px = (float)(x + (k % 3) - 1) + offx;
        float y0f = floorf(py), x0f = floorf(px);
        float wy1 = py - y0f, wx1 = px - x0f;
        int iy0 = (int)y0f, ix0 = (int)x0f;
        int iy1 = iy0 + 1;
        float wy0v = (iy0 >= 0 && iy0 < 64) ? (1.f - wy1) * ms : 0.f;
        float wy1v = (iy1 >= 0 && iy1 < 64) ? wy1 * ms : 0.f;
        int cy0 = min(max(iy0, 0), 63), cy1 = min(max(iy1, 0), 63);
        float xa, xb; int q;
        if (ix0 >= 0 && ix0 <= 62)      { q = ix0; xa = 1.f - wx1; xb = wx1;       }
        else if (ix0 == -1)             { q = 0;   xa = wx1;       xb = 0.f;       }
        else if (ix0 == 63)             { q = 62;  xa = 0.f;       xb = 1.f - wx1; }
        else                            { q = 0;   xa = 0.f;       xb = 0.f;       }
        sw0[e] = wy0v * xa;
        sw1[e] = wy0v * xb;
        sw2[e] = wy1v * xa;
        sw3[e] = wy1v * xb;
        si0[e] = (cy0 << 6) + q;
        si1[e] = (cy1 << 6) + q;
    }

    floatx4 acc[2];
    acc[0] = (floatx4){0.f, 0.f, 0.f, 0.f};
    acc[1] = (floatx4){0.f, 0.f, 0.f, 0.f};

    const int bp = tid & 15;           // pixel within tile
    const int cq = tid >> 4;           // 0..31, ONE channel each
    const int so = tid >> 1;           // A-stage row 0..255
    const int sh = tid & 1;            // A-stage half
    const size_t chbase = ((size_t)b * CB) << 12;
    const int mbase = wid * 32;

    __syncthreads();   // tables ready

    for (int cc = 0; cc < 8; cc++) {
        const int c0 = cc * 32;
        for (int tap = 0; tap < 9; tap++) {
            // A stage: w2bf[o][tap*256 + c0 .. c0+32)
            const unsigned short* gsrc =
                w2bf + (size_t)so * 2304 + tap * 256 + c0 + sh * 16;
            float4 v0 = *(const float4*)gsrc;
            float4 v1 = *(const float4*)(gsrc + 8);
            // B build: 1 channel for pixel bp, 1 aligned dword per row
            int tix = tap * 16 + bp;
            float w0 = sw0[tix], w1 = sw1[tix], w2v = sw2[tix], w3v = sw3[tix];
            int i0 = si0[tix], i1 = si1[tix];
            const unsigned short* bs0 = (i0 & 1) ? bfB : bfA;
            size_t co = chbase + ((size_t)(c0 + cq) << 12);
            unsigned int d0 = *(const unsigned int*)(bs0 + co + (i0 & ~1));
            unsigned int d1 = *(const unsigned int*)(bs0 + co + (i1 & ~1));
            float acv = w0 * __uint_as_float(d0 << 16)
                      + w1 * __uint_as_float(d0 & 0xffff0000u)
                      + w2v * __uint_as_float(d1 << 16)
                      + w3v * __uint_as_float(d1 & 0xffff0000u);
            unsigned short bv = f2bf(acv);
            *(float4*)((char*)As + so * 80 + sh * 32) = v0;
            *(float4*)((char*)As + so * 80 + sh * 32 + 16) = v1;
            *(unsigned short*)((char*)Bs + bp * 80 + cq * 2) = bv;
            __syncthreads();
            shortx8 af0 = *(const shortx8*)((const char*)As +
                          (mbase + l15) * 80 + quad * 16);
            shortx8 af1 = *(const shortx8*)((const char*)As +
                          (mbase + 16 + l15) * 80 + quad * 16);
            shortx8 bfr = *(const shortx8*)((const char*)Bs +
                          l15 * 80 + quad * 16);
            acc[0] = __builtin_amdgcn_mfma_f32_16x16x32_bf16(af0, bfr, acc[0], 0, 0, 0);
            acc[1] = __builtin_amdgcn_mfma_f32_16x16x32_bf16(af1, bfr, acc[1], 0, 0, 0);
            __syncthreads();
        }
    }

    // epilogue: D col = lane&15 (pixel), row = quad*4+reg
#pragma unroll
    for (int i = 0; i < 2; i++) {
#pragma unroll
        for (int r = 0; r < 4; r++) {
            int row = mbase + 16 * i + quad * 4 + r;
            out2[chbase + ((size_t)row << 12) + p0 + l15] = acc[i][r];
        }
    }
}

// ---------------------------------------------------------------------------
// Final: relu(gn3(d_out)*sc+bi + x) in place.
// ---------------------------------------------------------------------------
__global__ __launch_bounds__(256)
void final_k(float* __restrict__ dout, const float* __restrict__ x,
             const float2* __restrict__ stats, const float* __restrict__ sc,
             const float* __restrict__ bi) {
    long i = (long)blockIdx.x * 256 + threadIdx.x;
    long total4 = ((long)BATCH * CIN * PP) >> 2;
    if (i >= total4) return;
    long e = i << 2;
    int c = (int)((e >> 12) & 1023);
    int b = (int)(e >> 22);
    float2 st = stats[b * 32 + (c >> 5)];
    float a = st.y * sc[c];
    float bb = bi[c] - st.x * a;
    float4 v = ((float4*)dout)[i];
    float4 xv = ((const float4*)x)[i];
    v.x = fmaxf(v.x * a + bb + xv.x, 0.f);
    v.y = fmaxf(v.y * a + bb + xv.y, 0.f);
    v.z = fmaxf(v.z * a + bb + xv.z, 0.f);
    v.w = fmaxf(v.w * a + bb + xv.w, 0.f);
    ((float4*)dout)[i] = v;
}

// ---------------------------------------------------------------------------
// Workspace layout identical to R7/R8/R9 (50.9 MB, verified).
// ---------------------------------------------------------------------------
extern "C" void kernel_launch(void* const* d_in, const int* in_sizes, int n_in,
                              void* d_out, int out_size, void* d_ws, size_t ws_size,
                              hipStream_t stream) {
    const float* x   = (const float*)d_in[0];
    const float* w1  = (const float*)d_in[1];
    const float* g1s = (const float*)d_in[2];
    const float* g1b = (const float*)d_in[3];
    const float* wof = (const float*)d_in[4];
    const float* bof = (const float*)d_in[5];
    const float* w2  = (const float*)d_in[6];
    const float* g2s = (const float*)d_in[7];
    const float* g2b = (const float*)d_in[8];
    const float* w3  = (const float*)d_in[9];
    const float* g3s = (const float*)d_in[10];
    const float* g3b = (const float*)d_in[11];
    float* out = (float*)d_out;

    float* ws = (float*)d_ws;
    unsigned short* w1bf   = (unsigned short*)(ws + 0);
    float*          out1r  = ws + 131072;               // conv1 raw out
    float*          out2   = ws + 131072;               // aliases out1r (dead)
    unsigned short* xbfT   = (unsigned short*)(ws + 4325376);
    unsigned short* bfA    = (unsigned short*)(ws + 4325376);
    unsigned short* bfB    = (unsigned short*)(ws + 6422528);
    float*          om     = ws + 8519680;
    unsigned short* w2bf   = (unsigned short*)(ws + 8962048);
    unsigned short* out2bT = (unsigned short*)(ws + 4325376); // aliases bfA (dead)
    unsigned short* w3bf   = (unsigned short*)(ws + 11354112);
    float2* st1 = (float2*)(ws + 11485184);
    float2* st2 = st1 + 128;
    float2* st3 = st2 + 128;

    // x [b][1024][4096] -> xbfT [b][4096][1024] bf16
    transp_bf16<<<dim3(64, 16, 4), 256, 0, stream>>>(x, xbfT, 1024, 4096);
    cvt_bf16<<<1024, 256, 0, stream>>>(w1, w1bf, 262144);
    // conv1: out1r[b][256][4096] = w1bf @ xbfT   (xbfT dead after this)
    gemm_bf16<<<dim3(32, 2, 4), 256, 0, stream>>>(w1bf, xbfT, out1r, 256, 4096, 1024);
    gn_stats<<<128, 256, 0, stream>>>(out1r, st1, 256, 8);
    // GN1 apply -> bf16 bfA; shifted copy bfB
    gn1_apply_bf<<<4096, 256, 0, stream>>>(out1r, st1, g1s, g1b, bfA);
    mk_shift<<<16384, 256, 0, stream>>>(bfA, bfB);
    // offset conv (reads bfA)
    om_init<<<1728, 256, 0, stream>>>(om, bof);
    conv_off_k<<<dim3(16, 8, 4), 256, 0, stream>>>(bfA, wof, om);
    // weight conversions
    w2conv<<<2304, 256, 0, stream>>>(w2, w2bf);
    cvt_bf16<<<1024, 256, 0, stream>>>(w3, w3bf, 262144);
    // deformable einsum -> out2; 1024 blocks (16-px tiles), XCD<->batch swizzle
    gemm2_mfma<<<dim3(1024, 1, 1), 512, 0, stream>>>(bfA, bfB, w2bf, om, out2);
    // GN2 stats + fused apply/relu/transpose -> out2bT (bfA region, now dead)
    gn_stats<<<128, 256, 0, stream>>>(out2, st2, 256, 8);
    gn2t<<<dim3(64, 4, 4), 256, 0, stream>>>(out2, st2, g2s, g2b, out2bT);
    // conv3: out[b][1024][4096] = w3bf @ out2bT
    gemm_bf16<<<dim3(32, 8, 4), 256, 0, stream>>>(w3bf, out2bT, out, 1024, 4096, 256);
    gn_stats<<<128, 256, 0, stream>>>(out, st3, 1024, 32);
    final_k<<<16384, 256, 0, stream>>>(out, x, st3, g3s, g3b);
}

// Round 3
// 478.730 us; speedup vs baseline: 1.1168x; 1.1168x over previous
//
#include <hip/hip_runtime.h>
#include <math.h>

#define BATCH 4
#define CIN   1024
#define CB    256
#define HH    64
#define WW    64
#define PP    4096          // HH*WW
#define EPSV  1e-5f

using shortx8 = __attribute__((ext_vector_type(8))) short;
using floatx4 = __attribute__((ext_vector_type(4))) float;
using intx4   = __attribute__((ext_vector_type(4))) int;

static __device__ inline unsigned short f2bf(float f) {
    unsigned int u = __float_as_uint(f);
    u += 0x7fffu + ((u >> 16) & 1u);      // RNE
    return (unsigned short)(u >> 16);
}
static __device__ inline float bf2f(unsigned short s) {
    return __uint_as_float(((unsigned int)s) << 16);
}

// ---------------------------------------------------------------------------
// bf16 MFMA GEMM (conv1 / conv3). Unchanged from R4 (proven).
// ---------------------------------------------------------------------------
__global__ __launch_bounds__(256)
void gemm_bf16(const unsigned short* __restrict__ A,
               const unsigned short* __restrict__ BTg,
               float* __restrict__ Cg, int M, int N, int K) {
    const int b = blockIdx.z;
    const unsigned short* BT = BTg + (size_t)b * N * K;
    float* C = Cg + (size_t)b * M * N;
    const int m0 = blockIdx.y * 128;
    const int n0 = blockIdx.x * 128;
    const int tid = threadIdx.x;
    const int lane = tid & 63;
    const int wid = tid >> 6;
    const int l15 = lane & 15;
    const int quad = lane >> 4;

    __shared__ __align__(16) unsigned short As[128 * 40];
    __shared__ __align__(16) unsigned short Bs[128 * 40];

    floatx4 acc[2][8];
#pragma unroll
    for (int i = 0; i < 2; i++)
#pragma unroll
        for (int j = 0; j < 8; j++) acc[i][j] = (floatx4){0.f, 0.f, 0.f, 0.f};

    const int row = tid >> 1;
    const int half = tid & 1;

    for (int k0 = 0; k0 < K; k0 += 32) {
        const unsigned short* ga = A + (size_t)(m0 + row) * K + k0 + half * 16;
        const unsigned short* gb = BT + (size_t)(n0 + row) * K + k0 + half * 16;
        float4 a0 = *(const float4*)ga;
        float4 a1 = *(const float4*)(ga + 8);
        float4 b0 = *(const float4*)gb;
        float4 b1 = *(const float4*)(gb + 8);
        __syncthreads();
        *(float4*)((char*)As + row * 80 + half * 32) = a0;
        *(float4*)((char*)As + row * 80 + half * 32 + 16) = a1;
        *(float4*)((char*)Bs + row * 80 + half * 32) = b0;
        *(float4*)((char*)Bs + row * 80 + half * 32 + 16) = b1;
        __syncthreads();
        shortx8 af[2], bf[8];
#pragma unroll
        for (int i = 0; i < 2; i++)
            af[i] = *(const shortx8*)((const char*)As +
                    (wid * 32 + 16 * i + l15) * 80 + quad * 16);
#pragma unroll
        for (int j = 0; j < 8; j++)
            bf[j] = *(const shortx8*)((const char*)Bs +
                    (16 * j + l15) * 80 + quad * 16);
#pragma unroll
        for (int i = 0; i < 2; i++)
#pragma unroll
            for (int j = 0; j < 8; j++)
                acc[i][j] = __builtin_amdgcn_mfma_f32_16x16x32_bf16(
                    af[i], bf[j], acc[i][j], 0, 0, 0);
    }

#pragma unroll
    for (int i = 0; i < 2; i++) {
#pragma unroll
        for (int r = 0; r < 4; r++) {
            int m = m0 + wid * 32 + 16 * i + quad * 4 + r;
            float* dst = C + (size_t)m * N + n0 + l15;
#pragma unroll
            for (int j = 0; j < 8; j++)
                dst[16 * j] = acc[i][j][r];
        }
    }
}

// ---------------------------------------------------------------------------
// Tiled transpose + fp32->bf16: src [b][C][P] -> dst [b][P][C]
// ---------------------------------------------------------------------------
__global__ __launch_bounds__(256)
void transp_bf16(const float* __restrict__ src, unsigned short* __restrict__ dst,
                 int C, int P) {
    const int p0 = blockIdx.x * 64;
    const int c0 = blockIdx.y * 64;
    const int b = blockIdx.z;
    __shared__ unsigned short t[64][72];
    const float* s = src + ((size_t)b * C + c0) * P + p0;
    for (int e = threadIdx.x; e < 4096; e += 256) {
        int r = e >> 6, col = e & 63;
        t[r][col] = f2bf(s[(size_t)r * P + col]);
    }
    __syncthreads();
    unsigned short* d = dst + ((size_t)b * P + p0) * C + c0;
    for (int u = threadIdx.x; u < 512; u += 256) {
        int pr = u >> 3, c8 = (u & 7) * 8;
        ushort4 v0, v1;
        v0.x = t[c8 + 0][pr]; v0.y = t[c8 + 1][pr];
        v0.z = t[c8 + 2][pr]; v0.w = t[c8 + 3][pr];
        v1.x = t[c8 + 4][pr]; v1.y = t[c8 + 5][pr];
        v1.z = t[c8 + 6][pr]; v1.w = t[c8 + 7][pr];
        *(ushort4*)&d[(size_t)pr * C + c8] = v0;
        *(ushort4*)&d[(size_t)pr * C + c8 + 4] = v1;
    }
}

// ---------------------------------------------------------------------------
// GN2 apply + ReLU + transpose-convert: out2 fp32 [b][256][P] -> bf16 [b][P][256]
// ---------------------------------------------------------------------------
__global__ __launch_bounds__(256)
void gn2t(const float* __restrict__ src, const float2* __restrict__ st,
          const float* __restrict__ sc, const float* __restrict__ bi,
          unsigned short* __restrict__ dst) {
    const int p0 = blockIdx.x * 64;
    const int c0 = blockIdx.y * 64;
    const int b = blockIdx.z;
    __shared__ unsigned short t[64][72];
    const float* s = src + ((size_t)b * CB + c0) * PP + p0;
    for (int e = threadIdx.x; e < 4096; e += 256) {
        int r = e >> 6, col = e & 63;
        int c = c0 + r;
        float2 m = st[b * 32 + (c >> 3)];       // Cpg = 8
        float a = m.y * sc[c];
        float bb = bi[c] - m.x * a;
        t[r][col] = f2bf(fmaxf(s[(size_t)r * PP + col] * a + bb, 0.f));
    }
    __syncthreads();
    unsigned short* d = dst + ((size_t)b * PP + p0) * CB + c0;
    for (int u = threadIdx.x; u < 512; u += 256) {
        int pr = u >> 3, c8 = (u & 7) * 8;
        ushort4 v0, v1;
        v0.x = t[c8 + 0][pr]; v0.y = t[c8 + 1][pr];
        v0.z = t[c8 + 2][pr]; v0.w = t[c8 + 3][pr];
        v1.x = t[c8 + 4][pr]; v1.y = t[c8 + 5][pr];
        v1.z = t[c8 + 6][pr]; v1.w = t[c8 + 7][pr];
        *(ushort4*)&d[(size_t)pr * CB + c8] = v0;
        *(ushort4*)&d[(size_t)pr * CB + c8 + 4] = v1;
    }
}

// ---------------------------------------------------------------------------
__global__ __launch_bounds__(256)
void cvt_bf16(const float* __restrict__ s, unsigned short* __restrict__ d, int n) {
    int i = blockIdx.x * 256 + threadIdx.x;
    if (i < n) d[i] = f2bf(s[i]);
}

// ---------------------------------------------------------------------------
__global__ __launch_bounds__(256)
void gn_stats(const float* __restrict__ src, float2* __restrict__ stats,
              int C, int Cpg) {
    int bg = blockIdx.x;
    int b = bg >> 5, g = bg & 31;
    const float* base = src + ((size_t)b * C + (size_t)g * Cpg) * PP;
    int cnt = Cpg * PP;
    float s = 0.f, ss = 0.f;
    const float4* p4 = (const float4*)base;
    int n4 = cnt >> 2;
    for (int i = threadIdx.x; i < n4; i += 256) {
        float4 v = p4[i];
        s += v.x + v.y + v.z + v.w;
        ss += v.x * v.x + v.y * v.y + v.z * v.z + v.w * v.w;
    }
    for (int off = 32; off > 0; off >>= 1) {
        s += __shfl_down(s, off, 64);
        ss += __shfl_down(ss, off, 64);
    }
    __shared__ float rs[4], rss[4];
    int lane = threadIdx.x & 63, wid = threadIdx.x >> 6;
    if (lane == 0) { rs[wid] = s; rss[wid] = ss; }
    __syncthreads();
    if (threadIdx.x == 0) {
        float S = rs[0] + rs[1] + rs[2] + rs[3];
        float SS = rss[0] + rss[1] + rss[2] + rss[3];
        float mean = S / (float)cnt;
        float var = SS / (float)cnt - mean * mean;
        stats[bg] = make_float2(mean, rsqrtf(var + EPSV));
    }
}

// ---------------------------------------------------------------------------
// GN1 apply + ReLU, fp32 in -> bf16 out (bfA). C=256, Cpg=8 hardcoded.
// ---------------------------------------------------------------------------
__global__ __launch_bounds__(256)
void gn1_apply_bf(const float* __restrict__ src, const float2* __restrict__ stats,
                  const float* __restrict__ sc, const float* __restrict__ bi,
                  unsigned short* __restrict__ dst) {
    long i = (long)blockIdx.x * 256 + threadIdx.x;
    long total4 = ((long)BATCH * CB * PP) >> 2;
    if (i >= total4) return;
    long e = i << 2;
    int c = (int)((e >> 12) & 255);
    int b = (int)(e >> 20);
    float2 st = stats[b * 32 + (c >> 3)];
    float a = st.y * sc[c];
    float bb = bi[c] - st.x * a;
    float4 v = ((const float4*)src)[i];
    ushort4 o;
    o.x = f2bf(fmaxf(v.x * a + bb, 0.f));
    o.y = f2bf(fmaxf(v.y * a + bb, 0.f));
    o.z = f2bf(fmaxf(v.z * a + bb, 0.f));
    o.w = f2bf(fmaxf(v.w * a + bb, 0.f));
    ((ushort4*)dst)[i] = o;
}

// ---------------------------------------------------------------------------
// bfB[m] = bfA[m+1] (flat shift; boundary dwords never used by gathers).
// ---------------------------------------------------------------------------
__global__ __launch_bounds__(256)
void mk_shift(const unsigned short* __restrict__ a, unsigned short* __restrict__ bsh) {
    int t = blockIdx.x * 256 + threadIdx.x;
    uint2 d01 = ((const uint2*)a)[t];
    unsigned int d2 = ((const unsigned int*)a)[2 * t + 2];
    unsigned int w0 = (d01.x >> 16) | (d01.y << 16);
    unsigned int w1 = (d01.y >> 16) | (d2 << 16);
    ((uint2*)bsh)[t] = make_uint2(w0, w1);
}

// ---------------------------------------------------------------------------
__global__ __launch_bounds__(256)
void om_init(float* __restrict__ om, const float* __restrict__ boff) {
    int t = blockIdx.x * 256 + threadIdx.x;
    if (t < BATCH * 27 * PP) {
        int r = (t >> 12) % 27;
        om[t] = boff[r];
    }
}

// ---------------------------------------------------------------------------
// 3x3 offset conv (R8 version: 8-channel strip staging, 8 barriers total).
// ---------------------------------------------------------------------------
__global__ __launch_bounds__(256)
void conv_off_k(const unsigned short* __restrict__ o1bf, const float* __restrict__ w_off,
                float* __restrict__ om) {
    const int y0 = blockIdx.x * 4;
    const int c0 = blockIdx.y * 32;
    const int b = blockIdx.z;
    const int tid = threadIdx.x;
    const int tx = tid & 63, ty = tid >> 6;

    __shared__ __align__(16) float Aall[32 * 384];   // 48 KB
    __shared__ float strip[8 * 384];                 // 12 KB

    for (int e = tid; e < 32 * 384; e += 256) {
        int c = e / 384;
        int rk = e % 384;
        int r = rk / 12, k = rk % 12;
        float v = 0.f;
        if (r < 27 && k < 9) v = w_off[((size_t)r * CB + (c0 + c)) * 9 + k];
        Aall[e] = v;
    }

    float acc[8][4];
#pragma unroll
    for (int i = 0; i < 8; i++)
#pragma unroll
        for (int j = 0; j < 4; j++) acc[i][j] = 0.f;

    for (int cg = 0; cg < 4; cg++) {
        __syncthreads();
        for (int e = tid; e < 8 * 384; e += 256) {
            int c = e / 384, rk = e % 384;
            int r = rk >> 6, col = rk & 63;
            int gy = y0 + r - 1;
            strip[e] = (gy >= 0 && gy < 64)
                ? bf2f(o1bf[(((size_t)b * CB + c0 + cg * 8 + c) << 12) + (gy << 6) + col])
                : 0.f;
        }
        __syncthreads();
        for (int c = 0; c < 8; c++) {
            float v[6][3];
#pragma unroll
            for (int r = 0; r < 6; r++)
#pragma unroll
                for (int d = 0; d < 3; d++) {
                    int col = tx + d - 1;
                    v[r][d] = (col >= 0 && col < 64) ? strip[c * 384 + r * 64 + col] : 0.f;
                }
            const float* Ac = &Aall[(cg * 8 + c) * 384];
#pragma unroll
            for (int i = 0; i < 8; i++) {
                int m = ty + 4 * i;
                float4 w0 = *(const float4*)(Ac + m * 12);
                float4 w1v = *(const float4*)(Ac + m * 12 + 4);
                float w8 = Ac[m * 12 + 8];
                float wk[9] = {w0.x, w0.y, w0.z, w0.w, w1v.x, w1v.y, w1v.z, w1v.w, w8};
#pragma unroll
                for (int kk = 0; kk < 9; kk++) {
                    int dy = kk / 3, dx = kk % 3;
#pragma unroll
                    for (int j = 0; j < 4; j++)
                        acc[i][j] += wk[kk] * v[j + dy][dx];
                }
            }
        }
    }
#pragma unroll
    for (int i = 0; i < 8; i++) {
        int m = ty + 4 * i;
        if (m < 27) {
#pragma unroll
            for (int j = 0; j < 4; j++) {
                int p = ((y0 + j) << 6) + tx;
                atomicAdd(&om[((size_t)b * 27 + m) * PP + p], acc[i][j]);
            }
        }
    }
}

// ---------------------------------------------------------------------------
// w2 fp32 [o][c][tap] -> bf16, K reordered: w2bf[o][tap*256 + c]
// ---------------------------------------------------------------------------
__global__ __launch_bounds__(256)
void w2conv(const float* __restrict__ w2, unsigned short* __restrict__ w2bf) {
    int t = blockIdx.x * 256 + threadIdx.x;
    if (t >= 256 * 2304) return;
    int o = t / 2304;
    int r = t - o * 2304;
    int tap = r >> 8, c = r & 255;
    w2bf[t] = f2bf(w2[((size_t)o * 256 + c) * 9 + tap]);
}

// ---------------------------------------------------------------------------
// Deformable einsum, bf16 MFMA. R13: exact R10 structure (512 blocks x 512
// thr, 32-px tiles, two full barriers per segment — every deviation
// regressed), but channel-group loop unrolled x2: K=64 per segment ->
// 36 segments / 72 barriers instead of 72 / 144. R12 post-mortem: cost is
// dominated by fixed per-segment overhead (~2800 cy idle at barriers for
// gather-latency drain), so halve the segment count and double per-segment
// work + gather MLP (8 independent dwords/thread). A split As0/As1 keeps
// the proven 80B row stride (2-way LDS conflicts only). SoA tables kept
// (R11's one measured win: conflicts 1.12e7 -> 4.2e6).
// ---------------------------------------------------------------------------
__global__ __launch_bounds__(512, 4)
void gemm2_mfma(const unsigned short* __restrict__ bfA,
                const unsigned short* __restrict__ bfB,
                const unsigned short* __restrict__ w2bf,
                const float* __restrict__ om, float* __restrict__ out2) {
    const int blk = blockIdx.x;
    const int xcd = blk & 7;
    const int b = xcd >> 1;                          // batch per XCD-pair
    const int p0 = (((blk >> 3) << 1) | (xcd & 1)) * 32;
    const int tid = threadIdx.x;
    const int lane = tid & 63;
    const int wid = tid >> 6;          // 0..7
    const int l15 = lane & 15;
    const int quad = lane >> 4;        // 0..3

    __shared__ __align__(16) unsigned short As0[256 * 40];   // 20 KB (ch c0..c0+32)
    __shared__ __align__(16) unsigned short As1[256 * 40];   // 20 KB (ch c0+32..c0+64)
    __shared__ __align__(16) unsigned short Bs0[32 * 40];    // 2.5 KB
    __shared__ __align__(16) unsigned short Bs1[32 * 40];    // 2.5 KB
    __shared__ float sw0[288], sw1[288], sw2[288], sw3[288]; // SoA tables
    __shared__ int   si0[288], si1[288];

    // sampling tables (same math as R10, SoA layout), 9 taps x 32 pixels
    const float* ob = om + (size_t)b * 27 * PP;
    for (int e = tid; e < 288; e += 512) {
        int k = e >> 5, p = e & 31;
        int pg = p0 + p;
        float offx = ob[(size_t)k * PP + pg];
        float offy = ob[(size_t)(9 + k) * PP + pg];
        float ms = 1.f / (1.f + expf(-ob[(size_t)(18 + k) * PP + pg]));
        int y = pg >> 6, x = pg & 63;
        float py = (float)(y + k / 3 - 1) + offy;
        float px = (float)(x + (k % 3) - 1) + offx;
        float y0f = floorf(py), x0f = floorf(px);
        float wy1 = py - y0f, wx1 = px - x0f;
        int iy0 = (int)y0f, ix0 = (int)x0f;
        int iy1 = iy0 + 1;
        float wy0v = (iy0 >= 0 && iy0 < 64) ? (1.f - wy1) * ms : 0.f;
        float wy1v = (iy1 >= 0 && iy1 < 64) ? wy1 * ms : 0.f;
        int cy0 = min(max(iy0, 0), 63), cy1 = min(max(iy1, 0), 63);
        float xa, xb; int q;
        if (ix0 >= 0 && ix0 <= 62)      { q = ix0; xa = 1.f - wx1; xb = wx1;       }
        else if (ix0 == -1)             { q = 0;   xa = wx1;       xb = 0.f;       }
        else if (ix0 == 63)             { q = 62;  xa = 0.f;       xb = 1.f - wx1; }
        else                            { q = 0;   xa = 0.f;       xb = 0.f;       }
        sw0[e] = wy0v * xa;
        sw1[e] = wy0v * xb;
        sw2[e] = wy1v * xa;
        sw3[e] = wy1v * xb;
        si0[e] = (cy0 << 6) + q;
        si1[e] = (cy1 << 6) + q;
    }

    floatx4 acc[2][2];
#pragma unroll
    for (int i = 0; i < 2; i++)
#pragma unroll
        for (int j = 0; j < 2; j++) acc[i][j] = (floatx4){0.f, 0.f, 0.f, 0.f};

    const int bp = tid & 31;           // pixel within tile
    const int cq = tid >> 5;           // 0..15, 2 channels per half each
    const int so = tid >> 1;           // A-stage row 0..255
    const int sh = tid & 1;            // A-stage half (which 32-ch slice)
    const size_t chbase = ((size_t)b * CB) << 12;
    const int mbase = wid * 32;

    __syncthreads();   // tables ready

    for (int cc2 = 0; cc2 < 4; cc2++) {
        const int c0 = cc2 * 64;
        for (int tap = 0; tap < 9; tap++) {
            // A stage: w2bf[o][tap*256 + c0 .. c0+64); thread covers 32 ch (sh half)
            const unsigned short* gsrc =
                w2bf + (size_t)so * 2304 + tap * 256 + c0 + sh * 32;
            float4 a0 = *(const float4*)gsrc;
            float4 a1 = *(const float4*)(gsrc + 8);
            float4 a2 = *(const float4*)(gsrc + 16);
            float4 a3 = *(const float4*)(gsrc + 24);
            // B build: 2 channels x 2 halves for pixel bp -> 8 gather dwords
            int tix = tap * 32 + bp;
            float w0 = sw0[tix], w1 = sw1[tix], w2v = sw2[tix], w3v = sw3[tix];
            int i0 = si0[tix], i1 = si1[tix];
            const unsigned short* bs0 = (i0 & 1) ? bfB : bfA;
            unsigned short bv0[2], bv1[2];
#pragma unroll
            for (int s = 0; s < 2; s++) {
                size_t coA = chbase + ((size_t)(c0 + cq * 2 + s) << 12);
                size_t coB = coA + ((size_t)32 << 12);
                unsigned int d0 = *(const unsigned int*)(bs0 + coA + (i0 & ~1));
                unsigned int d1 = *(const unsigned int*)(bs0 + coA + (i1 & ~1));
                unsigned int e0 = *(const unsigned int*)(bs0 + coB + (i0 & ~1));
                unsigned int e1 = *(const unsigned int*)(bs0 + coB + (i1 & ~1));
                float va = w0 * __uint_as_float(d0 << 16)
                         + w1 * __uint_as_float(d0 & 0xffff0000u)
                         + w2v * __uint_as_float(d1 << 16)
                         + w3v * __uint_as_float(d1 & 0xffff0000u);
                float vb = w0 * __uint_as_float(e0 << 16)
                         + w1 * __uint_as_float(e0 & 0xffff0000u)
                         + w2v * __uint_as_float(e1 << 16)
                         + w3v * __uint_as_float(e1 & 0xffff0000u);
                bv0[s] = f2bf(va);
                bv1[s] = f2bf(vb);
            }
            unsigned short* adst = sh ? As1 : As0;
            *(float4*)((char*)adst + so * 80 +  0) = a0;
            *(float4*)((char*)adst + so * 80 + 16) = a1;
            *(float4*)((char*)adst + so * 80 + 32) = a2;
            *(float4*)((char*)adst + so * 80 + 48) = a3;
            *(ushort2*)((char*)Bs0 + bp * 80 + cq * 4) = make_ushort2(bv0[0], bv0[1]);
            *(ushort2*)((char*)Bs1 + bp * 80 + cq * 4) = make_ushort2(bv1[0], bv1[1]);
            __syncthreads();
            shortx8 af[2][2], bfr[2][2];
#pragma unroll
            for (int i = 0; i < 2; i++) {
                af[0][i] = *(const shortx8*)((const char*)As0 +
                           (mbase + 16 * i + l15) * 80 + quad * 16);
                af[1][i] = *(const shortx8*)((const char*)As1 +
                           (mbase + 16 * i + l15) * 80 + quad * 16);
                bfr[0][i] = *(const shortx8*)((const char*)Bs0 +
                            (16 * i + l15) * 80 + quad * 16);
                bfr[1][i] = *(const shortx8*)((const char*)Bs1 +
                            (16 * i + l15) * 80 + quad * 16);
            }
#pragma unroll
            for (int ks = 0; ks < 2; ks++)
#pragma unroll
                for (int i = 0; i < 2; i++)
#pragma unroll
                    for (int j = 0; j < 2; j++)
                        acc[i][j] = __builtin_amdgcn_mfma_f32_16x16x32_bf16(
                            af[ks][i], bfr[ks][j], acc[i][j], 0, 0, 0);
            __syncthreads();
        }
    }

    // epilogue: D col = lane&15 (pixel), row = quad*4+reg
#pragma unroll
    for (int i = 0; i < 2; i++) {
#pragma unroll
        for (int r = 0; r < 4; r++) {
            int row = mbase + 16 * i + quad * 4 + r;
            float* dst = out2 + chbase + ((size_t)row << 12) + p0 + l15;
#pragma unroll
            for (int j = 0; j < 2; j++)
                dst[16 * j] = acc[i][j][r];
        }
    }
}

// ---------------------------------------------------------------------------
// Final: relu(gn3(d_out)*sc+bi + x) in place.
// ---------------------------------------------------------------------------
__global__ __launch_bounds__(256)
void final_k(float* __restrict__ dout, const float* __restrict__ x,
             const float2* __restrict__ stats, const float* __restrict__ sc,
             const float* __restrict__ bi) {
    long i = (long)blockIdx.x * 256 + threadIdx.x;
    long total4 = ((long)BATCH * CIN * PP) >> 2;
    if (i >= total4) return;
    long e = i << 2;
    int c = (int)((e >> 12) & 1023);
    int b = (int)(e >> 22);
    float2 st = stats[b * 32 + (c >> 5)];
    float a = st.y * sc[c];
    float bb = bi[c] - st.x * a;
    float4 v = ((float4*)dout)[i];
    float4 xv = ((const float4*)x)[i];
    v.x = fmaxf(v.x * a + bb + xv.x, 0.f);
    v.y = fmaxf(v.y * a + bb + xv.y, 0.f);
    v.z = fmaxf(v.z * a + bb + xv.z, 0.f);
    v.w = fmaxf(v.w * a + bb + xv.w, 0.f);
    ((float4*)dout)[i] = v;
}

// ---------------------------------------------------------------------------
// Workspace layout identical to R7/R8/R9 (50.9 MB, verified).
// ---------------------------------------------------------------------------
extern "C" void kernel_launch(void* const* d_in, const int* in_sizes, int n_in,
                              void* d_out, int out_size, void* d_ws, size_t ws_size,
                              hipStream_t stream) {
    const float* x   = (const float*)d_in[0];
    const float* w1  = (const float*)d_in[1];
    const float* g1s = (const float*)d_in[2];
    const float* g1b = (const float*)d_in[3];
    const float* wof = (const float*)d_in[4];
    const float* bof = (const float*)d_in[5];
    const float* w2  = (const float*)d_in[6];
    const float* g2s = (const float*)d_in[7];
    const float* g2b = (const float*)d_in[8];
    const float* w3  = (const float*)d_in[9];
    const float* g3s = (const float*)d_in[10];
    const float* g3b = (const float*)d_in[11];
    float* out = (float*)d_out;

    float* ws = (float*)d_ws;
    unsigned short* w1bf   = (unsigned short*)(ws + 0);
    float*          out1r  = ws + 131072;               // conv1 raw out
    float*          out2   = ws + 131072;               // aliases out1r (dead)
    unsigned short* xbfT   = (unsigned short*)(ws + 4325376);
    unsigned short* bfA    = (unsigned short*)(ws + 4325376);
    unsigned short* bfB    = (unsigned short*)(ws + 6422528);
    float*          om     = ws + 8519680;
    unsigned short* w2bf   = (unsigned short*)(ws + 8962048);
    unsigned short* out2bT = (unsigned short*)(ws + 4325376); // aliases bfA (dead)
    unsigned short* w3bf   = (unsigned short*)(ws + 11354112);
    float2* st1 = (float2*)(ws + 11485184);
    float2* st2 = st1 + 128;
    float2* st3 = st2 + 128;

    // x [b][1024][4096] -> xbfT [b][4096][1024] bf16
    transp_bf16<<<dim3(64, 16, 4), 256, 0, stream>>>(x, xbfT, 1024, 4096);
    cvt_bf16<<<1024, 256, 0, stream>>>(w1, w1bf, 262144);
    // conv1: out1r[b][256][4096] = w1bf @ xbfT   (xbfT dead after this)
    gemm_bf16<<<dim3(32, 2, 4), 256, 0, stream>>>(w1bf, xbfT, out1r, 256, 4096, 1024);
    gn_stats<<<128, 256, 0, stream>>>(out1r, st1, 256, 8);
    // GN1 apply -> bf16 bfA; shifted copy bfB
    gn1_apply_bf<<<4096, 256, 0, stream>>>(out1r, st1, g1s, g1b, bfA);
    mk_shift<<<16384, 256, 0, stream>>>(bfA, bfB);
    // offset conv (reads bfA)
    om_init<<<1728, 256, 0, stream>>>(om, bof);
    conv_off_k<<<dim3(16, 8, 4), 256, 0, stream>>>(bfA, wof, om);
    // weight conversions
    w2conv<<<2304, 256, 0, stream>>>(w2, w2bf);
    cvt_bf16<<<1024, 256, 0, stream>>>(w3, w3bf, 262144);
    // deformable einsum -> out2; 512 linear blocks, XCD<->batch swizzle
    gemm2_mfma<<<dim3(512, 1, 1), 512, 0, stream>>>(bfA, bfB, w2bf, om, out2);
    // GN2 stats + fused apply/relu/transpose -> out2bT (bfA region, now dead)
    gn_stats<<<128, 256, 0, stream>>>(out2, st2, 256, 8);
    gn2t<<<dim3(64, 4, 4), 256, 0, stream>>>(out2, st2, g2s, g2b, out2bT);
    // conv3: out[b][1024][4096] = w3bf @ out2bT
    gemm_bf16<<<dim3(32, 8, 4), 256, 0, stream>>>(w3bf, out2bT, out, 1024, 4096, 256);
    gn_stats<<<128, 256, 0, stream>>>(out, st3, 1024, 32);
    final_k<<<16384, 256, 0, stream>>>(out, x, st3, g3s, g3b);
}

// Round 4
// 434.520 us; speedup vs baseline: 1.2304x; 1.1017x over previous
//
#include <hip/hip_runtime.h>
#include <math.h>

#define BATCH 4
#define CIN   1024
#define CB    256
#define HH    64
#define WW    64
#define PP    4096          // HH*WW
#define EPSV  1e-5f

using shortx8 = __attribute__((ext_vector_type(8))) short;
using floatx4 = __attribute__((ext_vector_type(4))) float;
using intx4   = __attribute__((ext_vector_type(4))) int;

static __device__ inline unsigned short f2bf(float f) {
    unsigned int u = __float_as_uint(f);
    u += 0x7fffu + ((u >> 16) & 1u);      // RNE
    return (unsigned short)(u >> 16);
}
static __device__ inline float bf2f(unsigned short s) {
    return __uint_as_float(((unsigned int)s) << 16);
}
static __device__ inline float bflo(unsigned int u) {
    return __uint_as_float(u << 16);
}
static __device__ inline float bfhi(unsigned int u) {
    return __uint_as_float(u & 0xffff0000u);
}

// ---------------------------------------------------------------------------
// bf16 MFMA GEMM (conv1 / conv3). Unchanged from R4 (proven).
// ---------------------------------------------------------------------------
__global__ __launch_bounds__(256)
void gemm_bf16(const unsigned short* __restrict__ A,
               const unsigned short* __restrict__ BTg,
               float* __restrict__ Cg, int M, int N, int K) {
    const int b = blockIdx.z;
    const unsigned short* BT = BTg + (size_t)b * N * K;
    float* C = Cg + (size_t)b * M * N;
    const int m0 = blockIdx.y * 128;
    const int n0 = blockIdx.x * 128;
    const int tid = threadIdx.x;
    const int lane = tid & 63;
    const int wid = tid >> 6;
    const int l15 = lane & 15;
    const int quad = lane >> 4;

    __shared__ __align__(16) unsigned short As[128 * 40];
    __shared__ __align__(16) unsigned short Bs[128 * 40];

    floatx4 acc[2][8];
#pragma unroll
    for (int i = 0; i < 2; i++)
#pragma unroll
        for (int j = 0; j < 8; j++) acc[i][j] = (floatx4){0.f, 0.f, 0.f, 0.f};

    const int row = tid >> 1;
    const int half = tid & 1;

    for (int k0 = 0; k0 < K; k0 += 32) {
        const unsigned short* ga = A + (size_t)(m0 + row) * K + k0 + half * 16;
        const unsigned short* gb = BT + (size_t)(n0 + row) * K + k0 + half * 16;
        float4 a0 = *(const float4*)ga;
        float4 a1 = *(const float4*)(ga + 8);
        float4 b0 = *(const float4*)gb;
        float4 b1 = *(const float4*)(gb + 8);
        __syncthreads();
        *(float4*)((char*)As + row * 80 + half * 32) = a0;
        *(float4*)((char*)As + row * 80 + half * 32 + 16) = a1;
        *(float4*)((char*)Bs + row * 80 + half * 32) = b0;
        *(float4*)((char*)Bs + row * 80 + half * 32 + 16) = b1;
        __syncthreads();
        shortx8 af[2], bf[8];
#pragma unroll
        for (int i = 0; i < 2; i++)
            af[i] = *(const shortx8*)((const char*)As +
                    (wid * 32 + 16 * i + l15) * 80 + quad * 16);
#pragma unroll
        for (int j = 0; j < 8; j++)
            bf[j] = *(const shortx8*)((const char*)Bs +
                    (16 * j + l15) * 80 + quad * 16);
#pragma unroll
        for (int i = 0; i < 2; i++)
#pragma unroll
            for (int j = 0; j < 8; j++)
                acc[i][j] = __builtin_amdgcn_mfma_f32_16x16x32_bf16(
                    af[i], bf[j], acc[i][j], 0, 0, 0);
    }

#pragma unroll
    for (int i = 0; i < 2; i++) {
#pragma unroll
        for (int r = 0; r < 4; r++) {
            int m = m0 + wid * 32 + 16 * i + quad * 4 + r;
            float* dst = C + (size_t)m * N + n0 + l15;
#pragma unroll
            for (int j = 0; j < 8; j++)
                dst[16 * j] = acc[i][j][r];
        }
    }
}

// ---------------------------------------------------------------------------
// Tiled transpose + fp32->bf16: src [b][C][P] -> dst [b][P][C]
// ---------------------------------------------------------------------------
__global__ __launch_bounds__(256)
void transp_bf16(const float* __restrict__ src, unsigned short* __restrict__ dst,
                 int C, int P) {
    const int p0 = blockIdx.x * 64;
    const int c0 = blockIdx.y * 64;
    const int b = blockIdx.z;
    __shared__ unsigned short t[64][72];
    const float* s = src + ((size_t)b * C + c0) * P + p0;
    for (int e = threadIdx.x; e < 4096; e += 256) {
        int r = e >> 6, col = e & 63;
        t[r][col] = f2bf(s[(size_t)r * P + col]);
    }
    __syncthreads();
    unsigned short* d = dst + ((size_t)b * P + p0) * C + c0;
    for (int u = threadIdx.x; u < 512; u += 256) {
        int pr = u >> 3, c8 = (u & 7) * 8;
        ushort4 v0, v1;
        v0.x = t[c8 + 0][pr]; v0.y = t[c8 + 1][pr];
        v0.z = t[c8 + 2][pr]; v0.w = t[c8 + 3][pr];
        v1.x = t[c8 + 4][pr]; v1.y = t[c8 + 5][pr];
        v1.z = t[c8 + 6][pr]; v1.w = t[c8 + 7][pr];
        *(ushort4*)&d[(size_t)pr * C + c8] = v0;
        *(ushort4*)&d[(size_t)pr * C + c8 + 4] = v1;
    }
}

// ---------------------------------------------------------------------------
// GN apply + ReLU + transpose-convert: src fp32 [b][256][P] -> bf16 [b][P][256]
// (C=256, Cpg=8 hardcoded; used for BOTH gn1->bfAT and gn2->out2bT)
// ---------------------------------------------------------------------------
__global__ __launch_bounds__(256)
void gn2t(const float* __restrict__ src, const float2* __restrict__ st,
          const float* __restrict__ sc, const float* __restrict__ bi,
          unsigned short* __restrict__ dst) {
    const int p0 = blockIdx.x * 64;
    const int c0 = blockIdx.y * 64;
    const int b = blockIdx.z;
    __shared__ unsigned short t[64][72];
    const float* s = src + ((size_t)b * CB + c0) * PP + p0;
    for (int e = threadIdx.x; e < 4096; e += 256) {
        int r = e >> 6, col = e & 63;
        int c = c0 + r;
        float2 m = st[b * 32 + (c >> 3)];       // Cpg = 8
        float a = m.y * sc[c];
        float bb = bi[c] - m.x * a;
        t[r][col] = f2bf(fmaxf(s[(size_t)r * PP + col] * a + bb, 0.f));
    }
    __syncthreads();
    unsigned short* d = dst + ((size_t)b * PP + p0) * CB + c0;
    for (int u = threadIdx.x; u < 512; u += 256) {
        int pr = u >> 3, c8 = (u & 7) * 8;
        ushort4 v0, v1;
        v0.x = t[c8 + 0][pr]; v0.y = t[c8 + 1][pr];
        v0.z = t[c8 + 2][pr]; v0.w = t[c8 + 3][pr];
        v1.x = t[c8 + 4][pr]; v1.y = t[c8 + 5][pr];
        v1.z = t[c8 + 6][pr]; v1.w = t[c8 + 7][pr];
        *(ushort4*)&d[(size_t)pr * CB + c8] = v0;
        *(ushort4*)&d[(size_t)pr * CB + c8 + 4] = v1;
    }
}

// ---------------------------------------------------------------------------
__global__ __launch_bounds__(256)
void cvt_bf16(const float* __restrict__ s, unsigned short* __restrict__ d, int n) {
    int i = blockIdx.x * 256 + threadIdx.x;
    if (i < n) d[i] = f2bf(s[i]);
}

// ---------------------------------------------------------------------------
__global__ __launch_bounds__(256)
void gn_stats(const float* __restrict__ src, float2* __restrict__ stats,
              int C, int Cpg) {
    int bg = blockIdx.x;
    int b = bg >> 5, g = bg & 31;
    const float* base = src + ((size_t)b * C + (size_t)g * Cpg) * PP;
    int cnt = Cpg * PP;
    float s = 0.f, ss = 0.f;
    const float4* p4 = (const float4*)base;
    int n4 = cnt >> 2;
    for (int i = threadIdx.x; i < n4; i += 256) {
        float4 v = p4[i];
        s += v.x + v.y + v.z + v.w;
        ss += v.x * v.x + v.y * v.y + v.z * v.z + v.w * v.w;
    }
    for (int off = 32; off > 0; off >>= 1) {
        s += __shfl_down(s, off, 64);
        ss += __shfl_down(ss, off, 64);
    }
    __shared__ float rs[4], rss[4];
    int lane = threadIdx.x & 63, wid = threadIdx.x >> 6;
    if (lane == 0) { rs[wid] = s; rss[wid] = ss; }
    __syncthreads();
    if (threadIdx.x == 0) {
        float S = rs[0] + rs[1] + rs[2] + rs[3];
        float SS = rss[0] + rss[1] + rss[2] + rss[3];
        float mean = S / (float)cnt;
        float var = SS / (float)cnt - mean * mean;
        stats[bg] = make_float2(mean, rsqrtf(var + EPSV));
    }
}

// ---------------------------------------------------------------------------
// GN1 apply + ReLU, fp32 in -> bf16 out (bfA, channel-major). For conv_off_k.
// ---------------------------------------------------------------------------
__global__ __launch_bounds__(256)
void gn1_apply_bf(const float* __restrict__ src, const float2* __restrict__ stats,
                  const float* __restrict__ sc, const float* __restrict__ bi,
                  unsigned short* __restrict__ dst) {
    long i = (long)blockIdx.x * 256 + threadIdx.x;
    long total4 = ((long)BATCH * CB * PP) >> 2;
    if (i >= total4) return;
    long e = i << 2;
    int c = (int)((e >> 12) & 255);
    int b = (int)(e >> 20);
    float2 st = stats[b * 32 + (c >> 3)];
    float a = st.y * sc[c];
    float bb = bi[c] - st.x * a;
    float4 v = ((const float4*)src)[i];
    ushort4 o;
    o.x = f2bf(fmaxf(v.x * a + bb, 0.f));
    o.y = f2bf(fmaxf(v.y * a + bb, 0.f));
    o.z = f2bf(fmaxf(v.z * a + bb, 0.f));
    o.w = f2bf(fmaxf(v.w * a + bb, 0.f));
    ((ushort4*)dst)[i] = o;
}

// ---------------------------------------------------------------------------
__global__ __launch_bounds__(256)
void om_init(float* __restrict__ om, const float* __restrict__ boff) {
    int t = blockIdx.x * 256 + threadIdx.x;
    if (t < BATCH * 27 * PP) {
        int r = (t >> 12) % 27;
        om[t] = boff[r];
    }
}

// ---------------------------------------------------------------------------
// 3x3 offset conv (R8 version: 8-channel strip staging, 8 barriers total).
// ---------------------------------------------------------------------------
__global__ __launch_bounds__(256)
void conv_off_k(const unsigned short* __restrict__ o1bf, const float* __restrict__ w_off,
                float* __restrict__ om) {
    const int y0 = blockIdx.x * 4;
    const int c0 = blockIdx.y * 32;
    const int b = blockIdx.z;
    const int tid = threadIdx.x;
    const int tx = tid & 63, ty = tid >> 6;

    __shared__ __align__(16) float Aall[32 * 384];   // 48 KB
    __shared__ float strip[8 * 384];                 // 12 KB

    for (int e = tid; e < 32 * 384; e += 256) {
        int c = e / 384;
        int rk = e % 384;
        int r = rk / 12, k = rk % 12;
        float v = 0.f;
        if (r < 27 && k < 9) v = w_off[((size_t)r * CB + (c0 + c)) * 9 + k];
        Aall[e] = v;
    }

    float acc[8][4];
#pragma unroll
    for (int i = 0; i < 8; i++)
#pragma unroll
        for (int j = 0; j < 4; j++) acc[i][j] = 0.f;

    for (int cg = 0; cg < 4; cg++) {
        __syncthreads();
        for (int e = tid; e < 8 * 384; e += 256) {
            int c = e / 384, rk = e % 384;
            int r = rk >> 6, col = rk & 63;
            int gy = y0 + r - 1;
            strip[e] = (gy >= 0 && gy < 64)
                ? bf2f(o1bf[(((size_t)b * CB + c0 + cg * 8 + c) << 12) + (gy << 6) + col])
                : 0.f;
        }
        __syncthreads();
        for (int c = 0; c < 8; c++) {
            float v[6][3];
#pragma unroll
            for (int r = 0; r < 6; r++)
#pragma unroll
                for (int d = 0; d < 3; d++) {
                    int col = tx + d - 1;
                    v[r][d] = (col >= 0 && col < 64) ? strip[c * 384 + r * 64 + col] : 0.f;
                }
            const float* Ac = &Aall[(cg * 8 + c) * 384];
#pragma unroll
            for (int i = 0; i < 8; i++) {
                int m = ty + 4 * i;
                float4 w0 = *(const float4*)(Ac + m * 12);
                float4 w1v = *(const float4*)(Ac + m * 12 + 4);
                float w8 = Ac[m * 12 + 8];
                float wk[9] = {w0.x, w0.y, w0.z, w0.w, w1v.x, w1v.y, w1v.z, w1v.w, w8};
#pragma unroll
                for (int kk = 0; kk < 9; kk++) {
                    int dy = kk / 3, dx = kk % 3;
#pragma unroll
                    for (int j = 0; j < 4; j++)
                        acc[i][j] += wk[kk] * v[j + dy][dx];
                }
            }
        }
    }
#pragma unroll
    for (int i = 0; i < 8; i++) {
        int m = ty + 4 * i;
        if (m < 27) {
#pragma unroll
            for (int j = 0; j < 4; j++) {
                int p = ((y0 + j) << 6) + tx;
                atomicAdd(&om[((size_t)b * 27 + m) * PP + p], acc[i][j]);
            }
        }
    }
}

// ---------------------------------------------------------------------------
// w2 fp32 [o][c][tap] -> bf16, K reordered: w2bf[o][tap*256 + c]
// ---------------------------------------------------------------------------
__global__ __launch_bounds__(256)
void w2conv(const float* __restrict__ w2, unsigned short* __restrict__ w2bf) {
    int t = blockIdx.x * 256 + threadIdx.x;
    if (t >= 256 * 2304) return;
    int o = t / 2304;
    int r = t - o * 2304;
    int tap = r >> 8, c = r & 255;
    w2bf[t] = f2bf(w2[((size_t)o * 256 + c) * 9 + tap]);
}

// ---------------------------------------------------------------------------
// Deformable einsum, bf16 MFMA. R14: R13 shell (512 blocks x 512 thr, 32-px
// tiles, K=64 segments, 72 barriers) with the gather rewritten for a
// PIXEL-MAJOR input bfAT [b][4096][256]. R13 post-mortem: cost scales with
// gather work; the saturated resource is the vector-memory address pipe /
// L2 request count (scattered dwords at 8KB channel stride = 1 L2 segment
// per lane). Pixel-major makes the 4 bilinear corners 512B-contiguous in
// channels: per thread 4x uint2 (4 contiguous ch per corner); lane map
// cq=tid&15 fast => each corner instr covers 4 pixels x 128B contiguous
// = ~8 L2 segments/instr instead of ~50. x+1 corner = row+1, so the bfB
// shifted copy and mk_shift are dead. Same FP order => bitwise-identical.
// ---------------------------------------------------------------------------
__global__ __launch_bounds__(512, 4)
void gemm2_mfma(const unsigned short* __restrict__ bfAT,
                const unsigned short* __restrict__ w2bf,
                const float* __restrict__ om, float* __restrict__ out2) {
    const int blk = blockIdx.x;
    const int xcd = blk & 7;
    const int b = xcd >> 1;                          // batch per XCD-pair
    const int p0 = (((blk >> 3) << 1) | (xcd & 1)) * 32;
    const int tid = threadIdx.x;
    const int lane = tid & 63;
    const int wid = tid >> 6;          // 0..7
    const int l15 = lane & 15;
    const int quad = lane >> 4;        // 0..3

    __shared__ __align__(16) unsigned short As0[256 * 40];   // 20 KB (ch c0..c0+32)
    __shared__ __align__(16) unsigned short As1[256 * 40];   // 20 KB (ch c0+32..c0+64)
    __shared__ __align__(16) unsigned short Bs0[32 * 40];    // 2.5 KB
    __shared__ __align__(16) unsigned short Bs1[32 * 40];    // 2.5 KB
    __shared__ float sw0[288], sw1[288], sw2[288], sw3[288]; // SoA tables
    __shared__ int   si0[288], si1[288];                     // row indices

    // sampling tables (same math as R13, SoA layout), 9 taps x 32 pixels
    const float* ob = om + (size_t)b * 27 * PP;
    for (int e = tid; e < 288; e += 512) {
        int k = e >> 5, p = e & 31;
        int pg = p0 + p;
        float offx = ob[(size_t)k * PP + pg];
        float offy = ob[(size_t)(9 + k) * PP + pg];
        float ms = 1.f / (1.f + expf(-ob[(size_t)(18 + k) * PP + pg]));
        int y = pg >> 6, x = pg & 63;
        float py = (float)(y + k / 3 - 1) + offy;
        float px = (float)(x + (k % 3) - 1) + offx;
        float y0f = floorf(py), x0f = floorf(px);
        float wy1 = py - y0f, wx1 = px - x0f;
        int iy0 = (int)y0f, ix0 = (int)x0f;
        int iy1 = iy0 + 1;
        float wy0v = (iy0 >= 0 && iy0 < 64) ? (1.f - wy1) * ms : 0.f;
        float wy1v = (iy1 >= 0 && iy1 < 64) ? wy1 * ms : 0.f;
        int cy0 = min(max(iy0, 0), 63), cy1 = min(max(iy1, 0), 63);
        float xa, xb; int q;
        if (ix0 >= 0 && ix0 <= 62)      { q = ix0; xa = 1.f - wx1; xb = wx1;       }
        else if (ix0 == -1)             { q = 0;   xa = wx1;       xb = 0.f;       }
        else if (ix0 == 63)             { q = 62;  xa = 0.f;       xb = 1.f - wx1; }
        else                            { q = 0;   xa = 0.f;       xb = 0.f;       }
        sw0[e] = wy0v * xa;            // corner (y0, q)   -> row r0
        sw1[e] = wy0v * xb;            // corner (y0, q+1) -> row r0+1
        sw2[e] = wy1v * xa;            // corner (y1, q)   -> row r1
        sw3[e] = wy1v * xb;            // corner (y1, q+1) -> row r1+1
        si0[e] = (cy0 << 6) + q;
        si1[e] = (cy1 << 6) + q;
    }

    floatx4 acc[2][2];
#pragma unroll
    for (int i = 0; i < 2; i++)
#pragma unroll
        for (int j = 0; j < 2; j++) acc[i][j] = (floatx4){0.f, 0.f, 0.f, 0.f};

    const int cq = tid & 15;           // channel quad (4 contiguous channels)
    const int bp = tid >> 4;           // pixel within tile 0..31
    const int so = tid >> 1;           // A-stage row 0..255
    const int sh = tid & 1;            // A-stage half (which 32-ch slice)
    const unsigned short* xbase = bfAT + (((size_t)b) << 20);   // b*PP*256
    const int mbase = wid * 32;

    __syncthreads();   // tables ready

    for (int cc2 = 0; cc2 < 4; cc2++) {
        const int c0 = cc2 * 64;
        for (int tap = 0; tap < 9; tap++) {
            // A stage: w2bf[o][tap*256 + c0 .. c0+64); thread covers 32 ch (sh half)
            const unsigned short* gsrc =
                w2bf + (size_t)so * 2304 + tap * 256 + c0 + sh * 32;
            float4 a0 = *(const float4*)gsrc;
            float4 a1 = *(const float4*)(gsrc + 8);
            float4 a2 = *(const float4*)(gsrc + 16);
            float4 a3 = *(const float4*)(gsrc + 24);
            // B gather: 4 bilinear corners x 4 contiguous channels (uint2 each)
            int tix = tap * 32 + bp;
            float w0 = sw0[tix], w1 = sw1[tix], w2v = sw2[tix], w3v = sw3[tix];
            int r0 = si0[tix], r1 = si1[tix];
            const unsigned short* gb = xbase + c0 + cq * 4;
            uint2 v00 = *(const uint2*)(gb + ((size_t)r0 << 8));
            uint2 v01 = *(const uint2*)(gb + ((size_t)(r0 + 1) << 8));
            uint2 v10 = *(const uint2*)(gb + ((size_t)r1 << 8));
            uint2 v11 = *(const uint2*)(gb + ((size_t)(r1 + 1) << 8));
            // interpolate 4 channels
            float f0 = w0 * bflo(v00.x) + w1 * bflo(v01.x)
                     + w2v * bflo(v10.x) + w3v * bflo(v11.x);
            float f1 = w0 * bfhi(v00.x) + w1 * bfhi(v01.x)
                     + w2v * bfhi(v10.x) + w3v * bfhi(v11.x);
            float f2 = w0 * bflo(v00.y) + w1 * bflo(v01.y)
                     + w2v * bflo(v10.y) + w3v * bflo(v11.y);
            float f3 = w0 * bfhi(v00.y) + w1 * bfhi(v01.y)
                     + w2v * bfhi(v10.y) + w3v * bfhi(v11.y);
            ushort4 bw = make_ushort4(f2bf(f0), f2bf(f1), f2bf(f2), f2bf(f3));
            // stage
            unsigned short* adst = sh ? As1 : As0;
            *(float4*)((char*)adst + so * 80 +  0) = a0;
            *(float4*)((char*)adst + so * 80 + 16) = a1;
            *(float4*)((char*)adst + so * 80 + 32) = a2;
            *(float4*)((char*)adst + so * 80 + 48) = a3;
            unsigned short* bdst = (cq & 8) ? Bs1 : Bs0;
            *(ushort4*)((char*)bdst + bp * 80 + (cq & 7) * 8) = bw;
            __syncthreads();
            shortx8 af[2][2], bfr[2][2];
#pragma unroll
            for (int i = 0; i < 2; i++) {
                af[0][i] = *(const shortx8*)((const char*)As0 +
                           (mbase + 16 * i + l15) * 80 + quad * 16);
                af[1][i] = *(const shortx8*)((const char*)As1 +
                           (mbase + 16 * i + l15) * 80 + quad * 16);
                bfr[0][i] = *(const shortx8*)((const char*)Bs0 +
                            (16 * i + l15) * 80 + quad * 16);
                bfr[1][i] = *(const shortx8*)((const char*)Bs1 +
                            (16 * i + l15) * 80 + quad * 16);
            }
#pragma unroll
            for (int ks = 0; ks < 2; ks++)
#pragma unroll
                for (int i = 0; i < 2; i++)
#pragma unroll
                    for (int j = 0; j < 2; j++)
                        acc[i][j] = __builtin_amdgcn_mfma_f32_16x16x32_bf16(
                            af[ks][i], bfr[ks][j], acc[i][j], 0, 0, 0);
            __syncthreads();
        }
    }

    // epilogue: D col = lane&15 (pixel), row = quad*4+reg
    const size_t chbase = ((size_t)b * CB) << 12;
#pragma unroll
    for (int i = 0; i < 2; i++) {
#pragma unroll
        for (int r = 0; r < 4; r++) {
            int row = mbase + 16 * i + quad * 4 + r;
            float* dst = out2 + chbase + ((size_t)row << 12) + p0 + l15;
#pragma unroll
            for (int j = 0; j < 2; j++)
                dst[16 * j] = acc[i][j][r];
        }
    }
}

// ---------------------------------------------------------------------------
// Final: relu(gn3(d_out)*sc+bi + x) in place.
// ---------------------------------------------------------------------------
__global__ __launch_bounds__(256)
void final_k(float* __restrict__ dout, const float* __restrict__ x,
             const float2* __restrict__ stats, const float* __restrict__ sc,
             const float* __restrict__ bi) {
    long i = (long)blockIdx.x * 256 + threadIdx.x;
    long total4 = ((long)BATCH * CIN * PP) >> 2;
    if (i >= total4) return;
    long e = i << 2;
    int c = (int)((e >> 12) & 1023);
    int b = (int)(e >> 22);
    float2 st = stats[b * 32 + (c >> 5)];
    float a = st.y * sc[c];
    float bb = bi[c] - st.x * a;
    float4 v = ((float4*)dout)[i];
    float4 xv = ((const float4*)x)[i];
    v.x = fmaxf(v.x * a + bb + xv.x, 0.f);
    v.y = fmaxf(v.y * a + bb + xv.y, 0.f);
    v.z = fmaxf(v.z * a + bb + xv.z, 0.f);
    v.w = fmaxf(v.w * a + bb + xv.w, 0.f);
    ((float4*)dout)[i] = v;
}

// ---------------------------------------------------------------------------
// Workspace layout: bfB slot (ws+6422528) repurposed as bfAT [b][4096][256].
// ---------------------------------------------------------------------------
extern "C" void kernel_launch(void* const* d_in, const int* in_sizes, int n_in,
                              void* d_out, int out_size, void* d_ws, size_t ws_size,
                              hipStream_t stream) {
    const float* x   = (const float*)d_in[0];
    const float* w1  = (const float*)d_in[1];
    const float* g1s = (const float*)d_in[2];
    const float* g1b = (const float*)d_in[3];
    const float* wof = (const float*)d_in[4];
    const float* bof = (const float*)d_in[5];
    const float* w2  = (const float*)d_in[6];
    const float* g2s = (const float*)d_in[7];
    const float* g2b = (const float*)d_in[8];
    const float* w3  = (const float*)d_in[9];
    const float* g3s = (const float*)d_in[10];
    const float* g3b = (const float*)d_in[11];
    float* out = (float*)d_out;

    float* ws = (float*)d_ws;
    unsigned short* w1bf   = (unsigned short*)(ws + 0);
    float*          out1r  = ws + 131072;               // conv1 raw out
    float*          out2   = ws + 131072;               // aliases out1r (dead)
    unsigned short* xbfT   = (unsigned short*)(ws + 4325376);
    unsigned short* bfA    = (unsigned short*)(ws + 4325376);
    unsigned short* bfAT   = (unsigned short*)(ws + 6422528);  // pixel-major GN1 out
    float*          om     = ws + 8519680;
    unsigned short* w2bf   = (unsigned short*)(ws + 8962048);
    unsigned short* out2bT = (unsigned short*)(ws + 4325376); // aliases bfA (dead)
    unsigned short* w3bf   = (unsigned short*)(ws + 11354112);
    float2* st1 = (float2*)(ws + 11485184);
    float2* st2 = st1 + 128;
    float2* st3 = st2 + 128;

    // x [b][1024][4096] -> xbfT [b][4096][1024] bf16
    transp_bf16<<<dim3(64, 16, 4), 256, 0, stream>>>(x, xbfT, 1024, 4096);
    cvt_bf16<<<1024, 256, 0, stream>>>(w1, w1bf, 262144);
    // conv1: out1r[b][256][4096] = w1bf @ xbfT   (xbfT dead after this)
    gemm_bf16<<<dim3(32, 2, 4), 256, 0, stream>>>(w1bf, xbfT, out1r, 256, 4096, 1024);
    gn_stats<<<128, 256, 0, stream>>>(out1r, st1, 256, 8);
    // GN1 apply -> bf16 bfA (channel-major, for conv_off)
    gn1_apply_bf<<<4096, 256, 0, stream>>>(out1r, st1, g1s, g1b, bfA);
    // GN1 apply -> bf16 bfAT (pixel-major, for deformable gather)
    gn2t<<<dim3(64, 4, 4), 256, 0, stream>>>(out1r, st1, g1s, g1b, bfAT);
    // offset conv (reads bfA)
    om_init<<<1728, 256, 0, stream>>>(om, bof);
    conv_off_k<<<dim3(16, 8, 4), 256, 0, stream>>>(bfA, wof, om);
    // weight conversions
    w2conv<<<2304, 256, 0, stream>>>(w2, w2bf);
    cvt_bf16<<<1024, 256, 0, stream>>>(w3, w3bf, 262144);
    // deformable einsum -> out2; 512 linear blocks, XCD<->batch swizzle
    gemm2_mfma<<<dim3(512, 1, 1), 512, 0, stream>>>(bfAT, w2bf, om, out2);
    // GN2 stats + fused apply/relu/transpose -> out2bT (bfA region, now dead)
    gn_stats<<<128, 256, 0, stream>>>(out2, st2, 256, 8);
    gn2t<<<dim3(64, 4, 4), 256, 0, stream>>>(out2, st2, g2s, g2b, out2bT);
    // conv3: out[b][1024][4096] = w3bf @ out2bT
    gemm_bf16<<<dim3(32, 8, 4), 256, 0, stream>>>(w3bf, out2bT, out, 1024, 4096, 256);
    gn_stats<<<128, 256, 0, stream>>>(out, st3, 1024, 32);
    final_k<<<16384, 256, 0, stream>>>(out, x, st3, g3s, g3b);
}

// Round 5
// 397.716 us; speedup vs baseline: 1.3443x; 1.0925x over previous
//
#include <hip/hip_runtime.h>
#include <math.h>

#define BATCH 4
#define CIN   1024
#define CB    256
#define HH    64
#define WW    64
#define PP    4096          // HH*WW
#define EPSV  1e-5f

using shortx8 = __attribute__((ext_vector_type(8))) short;
using floatx4 = __attribute__((ext_vector_type(4))) float;
using intx4   = __attribute__((ext_vector_type(4))) int;

static __device__ inline unsigned short f2bf(float f) {
    unsigned int u = __float_as_uint(f);
    u += 0x7fffu + ((u >> 16) & 1u);      // RNE
    return (unsigned short)(u >> 16);
}
static __device__ inline float bf2f(unsigned short s) {
    return __uint_as_float(((unsigned int)s) << 16);
}
static __device__ inline float bflo(unsigned int u) {
    return __uint_as_float(u << 16);
}
static __device__ inline float bfhi(unsigned int u) {
    return __uint_as_float(u & 0xffff0000u);
}

// ---------------------------------------------------------------------------
// bf16 MFMA GEMM (conv1 / conv3). Unchanged from R4 (proven).
// ---------------------------------------------------------------------------
__global__ __launch_bounds__(256)
void gemm_bf16(const unsigned short* __restrict__ A,
               const unsigned short* __restrict__ BTg,
               float* __restrict__ Cg, int M, int N, int K) {
    const int b = blockIdx.z;
    const unsigned short* BT = BTg + (size_t)b * N * K;
    float* C = Cg + (size_t)b * M * N;
    const int m0 = blockIdx.y * 128;
    const int n0 = blockIdx.x * 128;
    const int tid = threadIdx.x;
    const int lane = tid & 63;
    const int wid = tid >> 6;
    const int l15 = lane & 15;
    const int quad = lane >> 4;

    __shared__ __align__(16) unsigned short As[128 * 40];
    __shared__ __align__(16) unsigned short Bs[128 * 40];

    floatx4 acc[2][8];
#pragma unroll
    for (int i = 0; i < 2; i++)
#pragma unroll
        for (int j = 0; j < 8; j++) acc[i][j] = (floatx4){0.f, 0.f, 0.f, 0.f};

    const int row = tid >> 1;
    const int half = tid & 1;

    for (int k0 = 0; k0 < K; k0 += 32) {
        const unsigned short* ga = A + (size_t)(m0 + row) * K + k0 + half * 16;
        const unsigned short* gb = BT + (size_t)(n0 + row) * K + k0 + half * 16;
        float4 a0 = *(const float4*)ga;
        float4 a1 = *(const float4*)(ga + 8);
        float4 b0 = *(const float4*)gb;
        float4 b1 = *(const float4*)(gb + 8);
        __syncthreads();
        *(float4*)((char*)As + row * 80 + half * 32) = a0;
        *(float4*)((char*)As + row * 80 + half * 32 + 16) = a1;
        *(float4*)((char*)Bs + row * 80 + half * 32) = b0;
        *(float4*)((char*)Bs + row * 80 + half * 32 + 16) = b1;
        __syncthreads();
        shortx8 af[2], bf[8];
#pragma unroll
        for (int i = 0; i < 2; i++)
            af[i] = *(const shortx8*)((const char*)As +
                    (wid * 32 + 16 * i + l15) * 80 + quad * 16);
#pragma unroll
        for (int j = 0; j < 8; j++)
            bf[j] = *(const shortx8*)((const char*)Bs +
                    (16 * j + l15) * 80 + quad * 16);
#pragma unroll
        for (int i = 0; i < 2; i++)
#pragma unroll
            for (int j = 0; j < 8; j++)
                acc[i][j] = __builtin_amdgcn_mfma_f32_16x16x32_bf16(
                    af[i], bf[j], acc[i][j], 0, 0, 0);
    }

#pragma unroll
    for (int i = 0; i < 2; i++) {
#pragma unroll
        for (int r = 0; r < 4; r++) {
            int m = m0 + wid * 32 + 16 * i + quad * 4 + r;
            float* dst = C + (size_t)m * N + n0 + l15;
#pragma unroll
            for (int j = 0; j < 8; j++)
                dst[16 * j] = acc[i][j][r];
        }
    }
}

// ---------------------------------------------------------------------------
// Tiled transpose + fp32->bf16: src [b][C][P] -> dst [b][P][C]
// ---------------------------------------------------------------------------
__global__ __launch_bounds__(256)
void transp_bf16(const float* __restrict__ src, unsigned short* __restrict__ dst,
                 int C, int P) {
    const int p0 = blockIdx.x * 64;
    const int c0 = blockIdx.y * 64;
    const int b = blockIdx.z;
    __shared__ unsigned short t[64][72];
    const float* s = src + ((size_t)b * C + c0) * P + p0;
    for (int e = threadIdx.x; e < 4096; e += 256) {
        int r = e >> 6, col = e & 63;
        t[r][col] = f2bf(s[(size_t)r * P + col]);
    }
    __syncthreads();
    unsigned short* d = dst + ((size_t)b * P + p0) * C + c0;
    for (int u = threadIdx.x; u < 512; u += 256) {
        int pr = u >> 3, c8 = (u & 7) * 8;
        ushort4 v0, v1;
        v0.x = t[c8 + 0][pr]; v0.y = t[c8 + 1][pr];
        v0.z = t[c8 + 2][pr]; v0.w = t[c8 + 3][pr];
        v1.x = t[c8 + 4][pr]; v1.y = t[c8 + 5][pr];
        v1.z = t[c8 + 6][pr]; v1.w = t[c8 + 7][pr];
        *(ushort4*)&d[(size_t)pr * C + c8] = v0;
        *(ushort4*)&d[(size_t)pr * C + c8 + 4] = v1;
    }
}

// ---------------------------------------------------------------------------
// GN apply + ReLU + transpose-convert: src fp32 [b][256][P] -> bf16 [b][P][256]
// (used for gn2 -> out2bT)
// ---------------------------------------------------------------------------
__global__ __launch_bounds__(256)
void gn2t(const float* __restrict__ src, const float2* __restrict__ st,
          const float* __restrict__ sc, const float* __restrict__ bi,
          unsigned short* __restrict__ dst) {
    const int p0 = blockIdx.x * 64;
    const int c0 = blockIdx.y * 64;
    const int b = blockIdx.z;
    __shared__ unsigned short t[64][72];
    const float* s = src + ((size_t)b * CB + c0) * PP + p0;
    for (int e = threadIdx.x; e < 4096; e += 256) {
        int r = e >> 6, col = e & 63;
        int c = c0 + r;
        float2 m = st[b * 32 + (c >> 3)];       // Cpg = 8
        float a = m.y * sc[c];
        float bb = bi[c] - m.x * a;
        t[r][col] = f2bf(fmaxf(s[(size_t)r * PP + col] * a + bb, 0.f));
    }
    __syncthreads();
    unsigned short* d = dst + ((size_t)b * PP + p0) * CB + c0;
    for (int u = threadIdx.x; u < 512; u += 256) {
        int pr = u >> 3, c8 = (u & 7) * 8;
        ushort4 v0, v1;
        v0.x = t[c8 + 0][pr]; v0.y = t[c8 + 1][pr];
        v0.z = t[c8 + 2][pr]; v0.w = t[c8 + 3][pr];
        v1.x = t[c8 + 4][pr]; v1.y = t[c8 + 5][pr];
        v1.z = t[c8 + 6][pr]; v1.w = t[c8 + 7][pr];
        *(ushort4*)&d[(size_t)pr * CB + c8] = v0;
        *(ushort4*)&d[(size_t)pr * CB + c8 + 4] = v1;
    }
}

// ---------------------------------------------------------------------------
// GN1 dual-output: read out1r ONCE, write bfA (channel-major, for conv_off)
// AND bfAT (pixel-major, for the deformable gather). R15: merges the old
// gn1_apply_bf + gn2t(gn1) pair, saving one full 67MB fp32 read.
// ---------------------------------------------------------------------------
__global__ __launch_bounds__(256)
void gn1_dual(const float* __restrict__ src, const float2* __restrict__ st,
              const float* __restrict__ sc, const float* __restrict__ bi,
              unsigned short* __restrict__ dstC, unsigned short* __restrict__ dstT) {
    const int p0 = blockIdx.x * 64;
    const int c0 = blockIdx.y * 64;
    const int b = blockIdx.z;
    __shared__ unsigned short t[64][72];
    const float* s = src + ((size_t)b * CB + c0) * PP + p0;
    unsigned short* dc = dstC + ((size_t)b * CB + c0) * PP + p0;
    for (int e = threadIdx.x; e < 2048; e += 256) {
        int r = e >> 5, col = (e & 31) * 2;
        int c = c0 + r;
        float2 m = st[b * 32 + (c >> 3)];       // Cpg = 8
        float a = m.y * sc[c];
        float bb = bi[c] - m.x * a;
        float v0 = s[(size_t)r * PP + col];
        float v1 = s[(size_t)r * PP + col + 1];
        unsigned short q0 = f2bf(fmaxf(v0 * a + bb, 0.f));
        unsigned short q1 = f2bf(fmaxf(v1 * a + bb, 0.f));
        t[r][col] = q0;
        t[r][col + 1] = q1;
        *(ushort2*)&dc[(size_t)r * PP + col] = make_ushort2(q0, q1);
    }
    __syncthreads();
    unsigned short* d = dstT + ((size_t)b * PP + p0) * CB + c0;
    for (int u = threadIdx.x; u < 512; u += 256) {
        int pr = u >> 3, c8 = (u & 7) * 8;
        ushort4 v0, v1;
        v0.x = t[c8 + 0][pr]; v0.y = t[c8 + 1][pr];
        v0.z = t[c8 + 2][pr]; v0.w = t[c8 + 3][pr];
        v1.x = t[c8 + 4][pr]; v1.y = t[c8 + 5][pr];
        v1.z = t[c8 + 6][pr]; v1.w = t[c8 + 7][pr];
        *(ushort4*)&d[(size_t)pr * CB + c8] = v0;
        *(ushort4*)&d[(size_t)pr * CB + c8 + 4] = v1;
    }
}

// ---------------------------------------------------------------------------
__global__ __launch_bounds__(256)
void cvt_bf16(const float* __restrict__ s, unsigned short* __restrict__ d, int n) {
    int i = blockIdx.x * 256 + threadIdx.x;
    if (i < n) d[i] = f2bf(s[i]);
}

// ---------------------------------------------------------------------------
// GN stats, split 4-way per (b,group): 512 blocks (R15; the old 128-block
// version left half the CUs idle on a pure-BW kernel). Deterministic
// partial + finalize pair.
// ---------------------------------------------------------------------------
__global__ __launch_bounds__(256)
void gn_stats_part(const float* __restrict__ src, float2* __restrict__ part,
                   int C, int Cpg) {
    int bgs = blockIdx.x;
    int bg = bgs >> 2, s = bgs & 3;
    int b = bg >> 5, g = bg & 31;
    const float* base = src + ((size_t)b * C + (size_t)g * Cpg) * PP;
    int n4 = (Cpg * PP) >> 2;
    int per = n4 >> 2;
    const float4* p4 = (const float4*)base + (size_t)s * per;
    float sm = 0.f, ss = 0.f;
    for (int i = threadIdx.x; i < per; i += 256) {
        float4 v = p4[i];
        sm += v.x + v.y + v.z + v.w;
        ss += v.x * v.x + v.y * v.y + v.z * v.z + v.w * v.w;
    }
    for (int off = 32; off > 0; off >>= 1) {
        sm += __shfl_down(sm, off, 64);
        ss += __shfl_down(ss, off, 64);
    }
    __shared__ float rs[4], rss[4];
    int lane = threadIdx.x & 63, wid = threadIdx.x >> 6;
    if (lane == 0) { rs[wid] = sm; rss[wid] = ss; }
    __syncthreads();
    if (threadIdx.x == 0)
        part[bgs] = make_float2(rs[0] + rs[1] + rs[2] + rs[3],
                                rss[0] + rss[1] + rss[2] + rss[3]);
}

__global__ __launch_bounds__(128)
void gn_stats_fin(const float2* __restrict__ part, float2* __restrict__ stats,
                  int cnt) {
    int bg = threadIdx.x;           // 128 (b,g) pairs
    float2 p0 = part[bg * 4 + 0], p1 = part[bg * 4 + 1];
    float2 p2 = part[bg * 4 + 2], p3 = part[bg * 4 + 3];
    float S  = p0.x + p1.x + p2.x + p3.x;
    float SS = p0.y + p1.y + p2.y + p3.y;
    float mean = S / (float)cnt;
    float var = SS / (float)cnt - mean * mean;
    stats[bg] = make_float2(mean, rsqrtf(var + EPSV));
}

// ---------------------------------------------------------------------------
__global__ __launch_bounds__(256)
void om_init(float* __restrict__ om, const float* __restrict__ boff) {
    int t = blockIdx.x * 256 + threadIdx.x;
    if (t < BATCH * 27 * PP) {
        int r = (t >> 12) % 27;
        om[t] = boff[r];
    }
}

// ---------------------------------------------------------------------------
// 3x3 offset conv (R8 version: 8-channel strip staging, 8 barriers total).
// ---------------------------------------------------------------------------
__global__ __launch_bounds__(256)
void conv_off_k(const unsigned short* __restrict__ o1bf, const float* __restrict__ w_off,
                float* __restrict__ om) {
    const int y0 = blockIdx.x * 4;
    const int c0 = blockIdx.y * 32;
    const int b = blockIdx.z;
    const int tid = threadIdx.x;
    const int tx = tid & 63, ty = tid >> 6;

    __shared__ __align__(16) float Aall[32 * 384];   // 48 KB
    __shared__ float strip[8 * 384];                 // 12 KB

    for (int e = tid; e < 32 * 384; e += 256) {
        int c = e / 384;
        int rk = e % 384;
        int r = rk / 12, k = rk % 12;
        float v = 0.f;
        if (r < 27 && k < 9) v = w_off[((size_t)r * CB + (c0 + c)) * 9 + k];
        Aall[e] = v;
    }

    float acc[8][4];
#pragma unroll
    for (int i = 0; i < 8; i++)
#pragma unroll
        for (int j = 0; j < 4; j++) acc[i][j] = 0.f;

    for (int cg = 0; cg < 4; cg++) {
        __syncthreads();
        for (int e = tid; e < 8 * 384; e += 256) {
            int c = e / 384, rk = e % 384;
            int r = rk >> 6, col = rk & 63;
            int gy = y0 + r - 1;
            strip[e] = (gy >= 0 && gy < 64)
                ? bf2f(o1bf[(((size_t)b * CB + c0 + cg * 8 + c) << 12) + (gy << 6) + col])
                : 0.f;
        }
        __syncthreads();
        for (int c = 0; c < 8; c++) {
            float v[6][3];
#pragma unroll
            for (int r = 0; r < 6; r++)
#pragma unroll
                for (int d = 0; d < 3; d++) {
                    int col = tx + d - 1;
                    v[r][d] = (col >= 0 && col < 64) ? strip[c * 384 + r * 64 + col] : 0.f;
                }
            const float* Ac = &Aall[(cg * 8 + c) * 384];
#pragma unroll
            for (int i = 0; i < 8; i++) {
                int m = ty + 4 * i;
                float4 w0 = *(const float4*)(Ac + m * 12);
                float4 w1v = *(const float4*)(Ac + m * 12 + 4);
                float w8 = Ac[m * 12 + 8];
                float wk[9] = {w0.x, w0.y, w0.z, w0.w, w1v.x, w1v.y, w1v.z, w1v.w, w8};
#pragma unroll
                for (int kk = 0; kk < 9; kk++) {
                    int dy = kk / 3, dx = kk % 3;
#pragma unroll
                    for (int j = 0; j < 4; j++)
                        acc[i][j] += wk[kk] * v[j + dy][dx];
                }
            }
        }
    }
#pragma unroll
    for (int i = 0; i < 8; i++) {
        int m = ty + 4 * i;
        if (m < 27) {
#pragma unroll
            for (int j = 0; j < 4; j++) {
                int p = ((y0 + j) << 6) + tx;
                atomicAdd(&om[((size_t)b * 27 + m) * PP + p], acc[i][j]);
            }
        }
    }
}

// ---------------------------------------------------------------------------
// w2 fp32 [o][c][tap] -> bf16, K reordered: w2bf[o][tap*256 + c]
// ---------------------------------------------------------------------------
__global__ __launch_bounds__(256)
void w2conv(const float* __restrict__ w2, unsigned short* __restrict__ w2bf) {
    int t = blockIdx.x * 256 + threadIdx.x;
    if (t >= 256 * 2304) return;
    int o = t / 2304;
    int r = t - o * 2304;
    int tap = r >> 8, c = r & 255;
    w2bf[t] = f2bf(w2[((size_t)o * 256 + c) * 9 + tap]);
}

// ---------------------------------------------------------------------------
// Deformable einsum, bf16 MFMA. R15: R14 body (pixel-major coalesced
// gathers, proven −35%) + depth-1 REGISTER PREFETCH: segment t+1's A-loads
// and 4 corner loads are issued right after the first barrier of segment t,
// consumed at the top of t+1 — in-flight window = ds_read + 8 MFMA +
// barrier instead of ~0. R11's prefetch failed when the address pipe was
// saturated (throughput-bound); R14 removed that, leaving latency exposed
// (all pipes <20%), which prefetch CAN hide. Both full barriers and the
// staged As/Bs structure are kept exactly as proven.
// ---------------------------------------------------------------------------
__global__ __launch_bounds__(512, 4)
void gemm2_mfma(const unsigned short* __restrict__ bfAT,
                const unsigned short* __restrict__ w2bf,
                const float* __restrict__ om, float* __restrict__ out2) {
    const int blk = blockIdx.x;
    const int xcd = blk & 7;
    const int b = xcd >> 1;                          // batch per XCD-pair
    const int p0 = (((blk >> 3) << 1) | (xcd & 1)) * 32;
    const int tid = threadIdx.x;
    const int lane = tid & 63;
    const int wid = tid >> 6;          // 0..7
    const int l15 = lane & 15;
    const int quad = lane >> 4;        // 0..3

    __shared__ __align__(16) unsigned short As0[256 * 40];   // 20 KB
    __shared__ __align__(16) unsigned short As1[256 * 40];   // 20 KB
    __shared__ __align__(16) unsigned short Bs0[32 * 40];    // 2.5 KB
    __shared__ __align__(16) unsigned short Bs1[32 * 40];    // 2.5 KB
    __shared__ float sw0[288], sw1[288], sw2[288], sw3[288]; // SoA tables
    __shared__ int   si0[288], si1[288];                     // row indices

    // sampling tables (same math as R14), 9 taps x 32 pixels
    const float* ob = om + (size_t)b * 27 * PP;
    for (int e = tid; e < 288; e += 512) {
        int k = e >> 5, p = e & 31;
        int pg = p0 + p;
        float offx = ob[(size_t)k * PP + pg];
        float offy = ob[(size_t)(9 + k) * PP + pg];
        float ms = 1.f / (1.f + expf(-ob[(size_t)(18 + k) * PP + pg]));
        int y = pg >> 6, x = pg & 63;
        float py = (float)(y + k / 3 - 1) + offy;
        float px = (float)(x + (k % 3) - 1) + offx;
        float y0f = floorf(py), x0f = floorf(px);
        float wy1 = py - y0f, wx1 = px - x0f;
        int iy0 = (int)y0f, ix0 = (int)x0f;
        int iy1 = iy0 + 1;
        float wy0v = (iy0 >= 0 && iy0 < 64) ? (1.f - wy1) * ms : 0.f;
        float wy1v = (iy1 >= 0 && iy1 < 64) ? wy1 * ms : 0.f;
        int cy0 = min(max(iy0, 0), 63), cy1 = min(max(iy1, 0), 63);
        float xa, xb; int q;
        if (ix0 >= 0 && ix0 <= 62)      { q = ix0; xa = 1.f - wx1; xb = wx1;       }
        else if (ix0 == -1)             { q = 0;   xa = wx1;       xb = 0.f;       }
        else if (ix0 == 63)             { q = 62;  xa = 0.f;       xb = 1.f - wx1; }
        else                            { q = 0;   xa = 0.f;       xb = 0.f;       }
        sw0[e] = wy0v * xa;
        sw1[e] = wy0v * xb;
        sw2[e] = wy1v * xa;
        sw3[e] = wy1v * xb;
        si0[e] = (cy0 << 6) + q;
        si1[e] = (cy1 << 6) + q;
    }

    floatx4 acc[2][2];
#pragma unroll
    for (int i = 0; i < 2; i++)
#pragma unroll
        for (int j = 0; j < 2; j++) acc[i][j] = (floatx4){0.f, 0.f, 0.f, 0.f};

    const int cq = tid & 15;           // channel quad (4 contiguous channels)
    const int bp = tid >> 4;           // pixel within tile 0..31
    const int so = tid >> 1;           // A-stage row 0..255
    const int sh = tid & 1;            // A-stage half (which 32-ch slice)
    const unsigned short* xbase = bfAT + (((size_t)b) << 20);   // b*PP*256
    const unsigned short* abase = w2bf + (size_t)so * 2304 + sh * 32;
    const unsigned short* gbq = xbase + cq * 4;
    const int mbase = wid * 32;

    __syncthreads();   // tables ready

    // ---- prologue: issue loads for segment 0 (cc2=0, tap=0) ----
    float4 a0, a1, a2, a3;
    uint2 v00, v01, v10, v11;
    float w0, w1, w2v, w3v;
    {
        a0 = ((const float4*)abase)[0];
        a1 = ((const float4*)abase)[1];
        a2 = ((const float4*)abase)[2];
        a3 = ((const float4*)abase)[3];
        int tix = bp;
        w0 = sw0[tix]; w1 = sw1[tix]; w2v = sw2[tix]; w3v = sw3[tix];
        int r0 = si0[tix], r1 = si1[tix];
        v00 = *(const uint2*)(gbq + ((size_t)r0 << 8));
        v01 = *(const uint2*)(gbq + ((size_t)(r0 + 1) << 8));
        v10 = *(const uint2*)(gbq + ((size_t)r1 << 8));
        v11 = *(const uint2*)(gbq + ((size_t)(r1 + 1) << 8));
    }

    int tap = 0, cc2 = 0;
    for (int seg = 0; seg < 36; ++seg) {
        // ---- interp current (regs loaded one segment ago) + stage ----
        float f0 = w0 * bflo(v00.x) + w1 * bflo(v01.x)
                 + w2v * bflo(v10.x) + w3v * bflo(v11.x);
        float f1 = w0 * bfhi(v00.x) + w1 * bfhi(v01.x)
                 + w2v * bfhi(v10.x) + w3v * bfhi(v11.x);
        float f2 = w0 * bflo(v00.y) + w1 * bflo(v01.y)
                 + w2v * bflo(v10.y) + w3v * bflo(v11.y);
        float f3 = w0 * bfhi(v00.y) + w1 * bfhi(v01.y)
                 + w2v * bfhi(v10.y) + w3v * bfhi(v11.y);
        ushort4 bw = make_ushort4(f2bf(f0), f2bf(f1), f2bf(f2), f2bf(f3));
        unsigned short* adst = sh ? As1 : As0;
        *(float4*)((char*)adst + so * 80 +  0) = a0;
        *(float4*)((char*)adst + so * 80 + 16) = a1;
        *(float4*)((char*)adst + so * 80 + 32) = a2;
        *(float4*)((char*)adst + so * 80 + 48) = a3;
        unsigned short* bdst = (cq & 8) ? Bs1 : Bs0;
        *(ushort4*)((char*)bdst + bp * 80 + (cq & 7) * 8) = bw;
        __syncthreads();

        // ---- issue next segment's loads (hide under MFMA + barrier) ----
        int ntap = tap + 1, ncc2 = cc2;
        if (ntap == 9) { ntap = 0; ncc2 = (cc2 + 1) & 3; }
        {
            const unsigned short* gsrc = abase + ntap * 256 + ncc2 * 64;
            a0 = ((const float4*)gsrc)[0];
            a1 = ((const float4*)gsrc)[1];
            a2 = ((const float4*)gsrc)[2];
            a3 = ((const float4*)gsrc)[3];
            int tix = ntap * 32 + bp;
            int r0 = si0[tix], r1 = si1[tix];
            const unsigned short* gb = gbq + ncc2 * 64;
            v00 = *(const uint2*)(gb + ((size_t)r0 << 8));
            v01 = *(const uint2*)(gb + ((size_t)(r0 + 1) << 8));
            v10 = *(const uint2*)(gb + ((size_t)r1 << 8));
            v11 = *(const uint2*)(gb + ((size_t)(r1 + 1) << 8));
            w0 = sw0[tix]; w1 = sw1[tix]; w2v = sw2[tix]; w3v = sw3[tix];
        }

        // ---- MFMA on current LDS ----
        shortx8 af[2][2], bfr[2][2];
#pragma unroll
        for (int i = 0; i < 2; i++) {
            af[0][i] = *(const shortx8*)((const char*)As0 +
                       (mbase + 16 * i + l15) * 80 + quad * 16);
            af[1][i] = *(const shortx8*)((const char*)As1 +
                       (mbase + 16 * i + l15) * 80 + quad * 16);
            bfr[0][i] = *(const shortx8*)((const char*)Bs0 +
                        (16 * i + l15) * 80 + quad * 16);
            bfr[1][i] = *(const shortx8*)((const char*)Bs1 +
                        (16 * i + l15) * 80 + quad * 16);
        }
#pragma unroll
        for (int ks = 0; ks < 2; ks++)
#pragma unroll
            for (int i = 0; i < 2; i++)
#pragma unroll
                for (int j = 0; j < 2; j++)
                    acc[i][j] = __builtin_amdgcn_mfma_f32_16x16x32_bf16(
                        af[ks][i], bfr[ks][j], acc[i][j], 0, 0, 0);
        __syncthreads();
        tap = ntap; cc2 = ncc2;
    }

    // epilogue: D col = lane&15 (pixel), row = quad*4+reg
    const size_t chbase = ((size_t)b * CB) << 12;
#pragma unroll
    for (int i = 0; i < 2; i++) {
#pragma unroll
        for (int r = 0; r < 4; r++) {
            int row = mbase + 16 * i + quad * 4 + r;
            float* dst = out2 + chbase + ((size_t)row << 12) + p0 + l15;
#pragma unroll
            for (int j = 0; j < 2; j++)
                dst[16 * j] = acc[i][j][r];
        }
    }
}

// ---------------------------------------------------------------------------
// Final: relu(gn3(d_out)*sc+bi + x) in place.
// ---------------------------------------------------------------------------
__global__ __launch_bounds__(256)
void final_k(float* __restrict__ dout, const float* __restrict__ x,
             const float2* __restrict__ stats, const float* __restrict__ sc,
             const float* __restrict__ bi) {
    long i = (long)blockIdx.x * 256 + threadIdx.x;
    long total4 = ((long)BATCH * CIN * PP) >> 2;
    if (i >= total4) return;
    long e = i << 2;
    int c = (int)((e >> 12) & 1023);
    int b = (int)(e >> 22);
    float2 st = stats[b * 32 + (c >> 5)];
    float a = st.y * sc[c];
    float bb = bi[c] - st.x * a;
    float4 v = ((float4*)dout)[i];
    float4 xv = ((const float4*)x)[i];
    v.x = fmaxf(v.x * a + bb + xv.x, 0.f);
    v.y = fmaxf(v.y * a + bb + xv.y, 0.f);
    v.z = fmaxf(v.z * a + bb + xv.z, 0.f);
    v.w = fmaxf(v.w * a + bb + xv.w, 0.f);
    ((float4*)dout)[i] = v;
}

// ---------------------------------------------------------------------------
// Workspace layout: bfAT at ws+6422528 (pixel-major GN1 out); part buffer
// after st3.
// ---------------------------------------------------------------------------
extern "C" void kernel_launch(void* const* d_in, const int* in_sizes, int n_in,
                              void* d_out, int out_size, void* d_ws, size_t ws_size,
                              hipStream_t stream) {
    const float* x   = (const float*)d_in[0];
    const float* w1  = (const float*)d_in[1];
    const float* g1s = (const float*)d_in[2];
    const float* g1b = (const float*)d_in[3];
    const float* wof = (const float*)d_in[4];
    const float* bof = (const float*)d_in[5];
    const float* w2  = (const float*)d_in[6];
    const float* g2s = (const float*)d_in[7];
    const float* g2b = (const float*)d_in[8];
    const float* w3  = (const float*)d_in[9];
    const float* g3s = (const float*)d_in[10];
    const float* g3b = (const float*)d_in[11];
    float* out = (float*)d_out;

    float* ws = (float*)d_ws;
    unsigned short* w1bf   = (unsigned short*)(ws + 0);
    float*          out1r  = ws + 131072;               // conv1 raw out
    float*          out2   = ws + 131072;               // aliases out1r (dead)
    unsigned short* xbfT   = (unsigned short*)(ws + 4325376);
    unsigned short* bfA    = (unsigned short*)(ws + 4325376);
    unsigned short* bfAT   = (unsigned short*)(ws + 6422528);  // pixel-major GN1 out
    float*          om     = ws + 8519680;
    unsigned short* w2bf   = (unsigned short*)(ws + 8962048);
    unsigned short* out2bT = (unsigned short*)(ws + 4325376); // aliases bfA (dead)
    unsigned short* w3bf   = (unsigned short*)(ws + 11354112);
    float2* st1  = (float2*)(ws + 11485184);
    float2* st2  = st1 + 128;
    float2* st3  = st2 + 128;
    float2* part = st3 + 128;          // 512 float2 scratch for split stats

    // x [b][1024][4096] -> xbfT [b][4096][1024] bf16
    transp_bf16<<<dim3(64, 16, 4), 256, 0, stream>>>(x, xbfT, 1024, 4096);
    cvt_bf16<<<1024, 256, 0, stream>>>(w1, w1bf, 262144);
    // conv1: out1r[b][256][4096] = w1bf @ xbfT   (xbfT dead after this)
    gemm_bf16<<<dim3(32, 2, 4), 256, 0, stream>>>(w1bf, xbfT, out1r, 256, 4096, 1024);
    gn_stats_part<<<512, 256, 0, stream>>>(out1r, part, 256, 8);
    gn_stats_fin<<<1, 128, 0, stream>>>(part, st1, 8 * PP);
    // GN1 apply -> bfA (channel-major) + bfAT (pixel-major) in one pass
    gn1_dual<<<dim3(64, 4, 4), 256, 0, stream>>>(out1r, st1, g1s, g1b, bfA, bfAT);
    // offset conv (reads bfA)
    om_init<<<1728, 256, 0, stream>>>(om, bof);
    conv_off_k<<<dim3(16, 8, 4), 256, 0, stream>>>(bfA, wof, om);
    // weight conversions
    w2conv<<<2304, 256, 0, stream>>>(w2, w2bf);
    cvt_bf16<<<1024, 256, 0, stream>>>(w3, w3bf, 262144);
    // deformable einsum -> out2; 512 linear blocks, XCD<->batch swizzle
    gemm2_mfma<<<dim3(512, 1, 1), 512, 0, stream>>>(bfAT, w2bf, om, out2);
    // GN2 stats + fused apply/relu/transpose -> out2bT (bfA region, now dead)
    gn_stats_part<<<512, 256, 0, stream>>>(out2, part, 256, 8);
    gn_stats_fin<<<1, 128, 0, stream>>>(part, st2, 8 * PP);
    gn2t<<<dim3(64, 4, 4), 256, 0, stream>>>(out2, st2, g2s, g2b, out2bT);
    // conv3: out[b][1024][4096] = w3bf @ out2bT
    gemm_bf16<<<dim3(32, 8, 4), 256, 0, stream>>>(w3bf, out2bT, out, 1024, 4096, 256);
    gn_stats_part<<<512, 256, 0, stream>>>(out, part, 1024, 32);
    gn_stats_fin<<<1, 128, 0, stream>>>(part, st3, 32 * PP);
    final_k<<<16384, 256, 0, stream>>>(out, x, st3, g3s, g3b);
}

// Round 6
// 386.376 us; speedup vs baseline: 1.3837x; 1.0294x over previous
//
#include <hip/hip_runtime.h>
#include <math.h>

#define BATCH 4
#define CIN   1024
#define CB    256
#define HH    64
#define WW    64
#define PP    4096          // HH*WW
#define EPSV  1e-5f

using shortx8 = __attribute__((ext_vector_type(8))) short;
using floatx4 = __attribute__((ext_vector_type(4))) float;
using intx4   = __attribute__((ext_vector_type(4))) int;

static __device__ inline unsigned short f2bf(float f) {
    unsigned int u = __float_as_uint(f);
    u += 0x7fffu + ((u >> 16) & 1u);      // RNE
    return (unsigned short)(u >> 16);
}
static __device__ inline float bf2f(unsigned short s) {
    return __uint_as_float(((unsigned int)s) << 16);
}
static __device__ inline float bflo(unsigned int u) {
    return __uint_as_float(u << 16);
}
static __device__ inline float bfhi(unsigned int u) {
    return __uint_as_float(u & 0xffff0000u);
}

// ---------------------------------------------------------------------------
// bf16 MFMA GEMM (conv1 / conv3). Unchanged from R4 (proven).
// ---------------------------------------------------------------------------
__global__ __launch_bounds__(256)
void gemm_bf16(const unsigned short* __restrict__ A,
               const unsigned short* __restrict__ BTg,
               float* __restrict__ Cg, int M, int N, int K) {
    const int b = blockIdx.z;
    const unsigned short* BT = BTg + (size_t)b * N * K;
    float* C = Cg + (size_t)b * M * N;
    const int m0 = blockIdx.y * 128;
    const int n0 = blockIdx.x * 128;
    const int tid = threadIdx.x;
    const int lane = tid & 63;
    const int wid = tid >> 6;
    const int l15 = lane & 15;
    const int quad = lane >> 4;

    __shared__ __align__(16) unsigned short As[128 * 40];
    __shared__ __align__(16) unsigned short Bs[128 * 40];

    floatx4 acc[2][8];
#pragma unroll
    for (int i = 0; i < 2; i++)
#pragma unroll
        for (int j = 0; j < 8; j++) acc[i][j] = (floatx4){0.f, 0.f, 0.f, 0.f};

    const int row = tid >> 1;
    const int half = tid & 1;

    for (int k0 = 0; k0 < K; k0 += 32) {
        const unsigned short* ga = A + (size_t)(m0 + row) * K + k0 + half * 16;
        const unsigned short* gb = BT + (size_t)(n0 + row) * K + k0 + half * 16;
        float4 a0 = *(const float4*)ga;
        float4 a1 = *(const float4*)(ga + 8);
        float4 b0 = *(const float4*)gb;
        float4 b1 = *(const float4*)(gb + 8);
        __syncthreads();
        *(float4*)((char*)As + row * 80 + half * 32) = a0;
        *(float4*)((char*)As + row * 80 + half * 32 + 16) = a1;
        *(float4*)((char*)Bs + row * 80 + half * 32) = b0;
        *(float4*)((char*)Bs + row * 80 + half * 32 + 16) = b1;
        __syncthreads();
        shortx8 af[2], bf[8];
#pragma unroll
        for (int i = 0; i < 2; i++)
            af[i] = *(const shortx8*)((const char*)As +
                    (wid * 32 + 16 * i + l15) * 80 + quad * 16);
#pragma unroll
        for (int j = 0; j < 8; j++)
            bf[j] = *(const shortx8*)((const char*)Bs +
                    (16 * j + l15) * 80 + quad * 16);
#pragma unroll
        for (int i = 0; i < 2; i++)
#pragma unroll
            for (int j = 0; j < 8; j++)
                acc[i][j] = __builtin_amdgcn_mfma_f32_16x16x32_bf16(
                    af[i], bf[j], acc[i][j], 0, 0, 0);
    }

#pragma unroll
    for (int i = 0; i < 2; i++) {
#pragma unroll
        for (int r = 0; r < 4; r++) {
            int m = m0 + wid * 32 + 16 * i + quad * 4 + r;
            float* dst = C + (size_t)m * N + n0 + l15;
#pragma unroll
            for (int j = 0; j < 8; j++)
                dst[16 * j] = acc[i][j][r];
        }
    }
}

// ---------------------------------------------------------------------------
// Tiled transpose + fp32->bf16: src [b][C][P] -> dst [b][P][C]
// ---------------------------------------------------------------------------
__global__ __launch_bounds__(256)
void transp_bf16(const float* __restrict__ src, unsigned short* __restrict__ dst,
                 int C, int P) {
    const int p0 = blockIdx.x * 64;
    const int c0 = blockIdx.y * 64;
    const int b = blockIdx.z;
    __shared__ unsigned short t[64][72];
    const float* s = src + ((size_t)b * C + c0) * P + p0;
    for (int e = threadIdx.x; e < 4096; e += 256) {
        int r = e >> 6, col = e & 63;
        t[r][col] = f2bf(s[(size_t)r * P + col]);
    }
    __syncthreads();
    unsigned short* d = dst + ((size_t)b * P + p0) * C + c0;
    for (int u = threadIdx.x; u < 512; u += 256) {
        int pr = u >> 3, c8 = (u & 7) * 8;
        ushort4 v0, v1;
        v0.x = t[c8 + 0][pr]; v0.y = t[c8 + 1][pr];
        v0.z = t[c8 + 2][pr]; v0.w = t[c8 + 3][pr];
        v1.x = t[c8 + 4][pr]; v1.y = t[c8 + 5][pr];
        v1.z = t[c8 + 6][pr]; v1.w = t[c8 + 7][pr];
        *(ushort4*)&d[(size_t)pr * C + c8] = v0;
        *(ushort4*)&d[(size_t)pr * C + c8 + 4] = v1;
    }
}

// ---------------------------------------------------------------------------
// GN apply + ReLU + transpose-convert: src fp32 [b][256][P] -> bf16 [b][P][256]
// (used for gn2 -> out2bT)
// ---------------------------------------------------------------------------
__global__ __launch_bounds__(256)
void gn2t(const float* __restrict__ src, const float2* __restrict__ st,
          const float* __restrict__ sc, const float* __restrict__ bi,
          unsigned short* __restrict__ dst) {
    const int p0 = blockIdx.x * 64;
    const int c0 = blockIdx.y * 64;
    const int b = blockIdx.z;
    __shared__ unsigned short t[64][72];
    const float* s = src + ((size_t)b * CB + c0) * PP + p0;
    for (int e = threadIdx.x; e < 4096; e += 256) {
        int r = e >> 6, col = e & 63;
        int c = c0 + r;
        float2 m = st[b * 32 + (c >> 3)];       // Cpg = 8
        float a = m.y * sc[c];
        float bb = bi[c] - m.x * a;
        t[r][col] = f2bf(fmaxf(s[(size_t)r * PP + col] * a + bb, 0.f));
    }
    __syncthreads();
    unsigned short* d = dst + ((size_t)b * PP + p0) * CB + c0;
    for (int u = threadIdx.x; u < 512; u += 256) {
        int pr = u >> 3, c8 = (u & 7) * 8;
        ushort4 v0, v1;
        v0.x = t[c8 + 0][pr]; v0.y = t[c8 + 1][pr];
        v0.z = t[c8 + 2][pr]; v0.w = t[c8 + 3][pr];
        v1.x = t[c8 + 4][pr]; v1.y = t[c8 + 5][pr];
        v1.z = t[c8 + 6][pr]; v1.w = t[c8 + 7][pr];
        *(ushort4*)&d[(size_t)pr * CB + c8] = v0;
        *(ushort4*)&d[(size_t)pr * CB + c8 + 4] = v1;
    }
}

// ---------------------------------------------------------------------------
// GN1 dual-output: read out1r ONCE, write bfA (channel-major, for conv_off)
// AND bfAT (pixel-major, for the deformable gather).
// ---------------------------------------------------------------------------
__global__ __launch_bounds__(256)
void gn1_dual(const float* __restrict__ src, const float2* __restrict__ st,
              const float* __restrict__ sc, const float* __restrict__ bi,
              unsigned short* __restrict__ dstC, unsigned short* __restrict__ dstT) {
    const int p0 = blockIdx.x * 64;
    const int c0 = blockIdx.y * 64;
    const int b = blockIdx.z;
    __shared__ unsigned short t[64][72];
    const float* s = src + ((size_t)b * CB + c0) * PP + p0;
    unsigned short* dc = dstC + ((size_t)b * CB + c0) * PP + p0;
    for (int e = threadIdx.x; e < 2048; e += 256) {
        int r = e >> 5, col = (e & 31) * 2;
        int c = c0 + r;
        float2 m = st[b * 32 + (c >> 3)];       // Cpg = 8
        float a = m.y * sc[c];
        float bb = bi[c] - m.x * a;
        float v0 = s[(size_t)r * PP + col];
        float v1 = s[(size_t)r * PP + col + 1];
        unsigned short q0 = f2bf(fmaxf(v0 * a + bb, 0.f));
        unsigned short q1 = f2bf(fmaxf(v1 * a + bb, 0.f));
        t[r][col] = q0;
        t[r][col + 1] = q1;
        *(ushort2*)&dc[(size_t)r * PP + col] = make_ushort2(q0, q1);
    }
    __syncthreads();
    unsigned short* d = dstT + ((size_t)b * PP + p0) * CB + c0;
    for (int u = threadIdx.x; u < 512; u += 256) {
        int pr = u >> 3, c8 = (u & 7) * 8;
        ushort4 v0, v1;
        v0.x = t[c8 + 0][pr]; v0.y = t[c8 + 1][pr];
        v0.z = t[c8 + 2][pr]; v0.w = t[c8 + 3][pr];
        v1.x = t[c8 + 4][pr]; v1.y = t[c8 + 5][pr];
        v1.z = t[c8 + 6][pr]; v1.w = t[c8 + 7][pr];
        *(ushort4*)&d[(size_t)pr * CB + c8] = v0;
        *(ushort4*)&d[(size_t)pr * CB + c8 + 4] = v1;
    }
}

// ---------------------------------------------------------------------------
__global__ __launch_bounds__(256)
void cvt_bf16(const float* __restrict__ s, unsigned short* __restrict__ d, int n) {
    int i = blockIdx.x * 256 + threadIdx.x;
    if (i < n) d[i] = f2bf(s[i]);
}

// ---------------------------------------------------------------------------
// GN stats, split 4-way per (b,group): 512 blocks. Partial + finalize.
// ---------------------------------------------------------------------------
__global__ __launch_bounds__(256)
void gn_stats_part(const float* __restrict__ src, float2* __restrict__ part,
                   int C, int Cpg) {
    int bgs = blockIdx.x;
    int bg = bgs >> 2, s = bgs & 3;
    int b = bg >> 5, g = bg & 31;
    const float* base = src + ((size_t)b * C + (size_t)g * Cpg) * PP;
    int n4 = (Cpg * PP) >> 2;
    int per = n4 >> 2;
    const float4* p4 = (const float4*)base + (size_t)s * per;
    float sm = 0.f, ss = 0.f;
    for (int i = threadIdx.x; i < per; i += 256) {
        float4 v = p4[i];
        sm += v.x + v.y + v.z + v.w;
        ss += v.x * v.x + v.y * v.y + v.z * v.z + v.w * v.w;
    }
    for (int off = 32; off > 0; off >>= 1) {
        sm += __shfl_down(sm, off, 64);
        ss += __shfl_down(ss, off, 64);
    }
    __shared__ float rs[4], rss[4];
    int lane = threadIdx.x & 63, wid = threadIdx.x >> 6;
    if (lane == 0) { rs[wid] = sm; rss[wid] = ss; }
    __syncthreads();
    if (threadIdx.x == 0)
        part[bgs] = make_float2(rs[0] + rs[1] + rs[2] + rs[3],
                                rss[0] + rss[1] + rss[2] + rss[3]);
}

__global__ __launch_bounds__(128)
void gn_stats_fin(const float2* __restrict__ part, float2* __restrict__ stats,
                  int cnt) {
    int bg = threadIdx.x;           // 128 (b,g) pairs
    float2 p0 = part[bg * 4 + 0], p1 = part[bg * 4 + 1];
    float2 p2 = part[bg * 4 + 2], p3 = part[bg * 4 + 3];
    float S  = p0.x + p1.x + p2.x + p3.x;
    float SS = p0.y + p1.y + p2.y + p3.y;
    float mean = S / (float)cnt;
    float var = SS / (float)cnt - mean * mean;
    stats[bg] = make_float2(mean, rsqrtf(var + EPSV));
}

// ---------------------------------------------------------------------------
__global__ __launch_bounds__(256)
void om_init(float* __restrict__ om, const float* __restrict__ boff) {
    int t = blockIdx.x * 256 + threadIdx.x;
    if (t < BATCH * 27 * PP) {
        int r = (t >> 12) % 27;
        om[t] = boff[r];
    }
}

// ---------------------------------------------------------------------------
// 3x3 offset conv (R8 version: 8-channel strip staging, 8 barriers total).
// ---------------------------------------------------------------------------
__global__ __launch_bounds__(256)
void conv_off_k(const unsigned short* __restrict__ o1bf, const float* __restrict__ w_off,
                float* __restrict__ om) {
    const int y0 = blockIdx.x * 4;
    const int c0 = blockIdx.y * 32;
    const int b = blockIdx.z;
    const int tid = threadIdx.x;
    const int tx = tid & 63, ty = tid >> 6;

    __shared__ __align__(16) float Aall[32 * 384];   // 48 KB
    __shared__ float strip[8 * 384];                 // 12 KB

    for (int e = tid; e < 32 * 384; e += 256) {
        int c = e / 384;
        int rk = e % 384;
        int r = rk / 12, k = rk % 12;
        float v = 0.f;
        if (r < 27 && k < 9) v = w_off[((size_t)r * CB + (c0 + c)) * 9 + k];
        Aall[e] = v;
    }

    float acc[8][4];
#pragma unroll
    for (int i = 0; i < 8; i++)
#pragma unroll
        for (int j = 0; j < 4; j++) acc[i][j] = 0.f;

    for (int cg = 0; cg < 4; cg++) {
        __syncthreads();
        for (int e = tid; e < 8 * 384; e += 256) {
            int c = e / 384, rk = e % 384;
            int r = rk >> 6, col = rk & 63;
            int gy = y0 + r - 1;
            strip[e] = (gy >= 0 && gy < 64)
                ? bf2f(o1bf[(((size_t)b * CB + c0 + cg * 8 + c) << 12) + (gy << 6) + col])
                : 0.f;
        }
        __syncthreads();
        for (int c = 0; c < 8; c++) {
            float v[6][3];
#pragma unroll
            for (int r = 0; r < 6; r++)
#pragma unroll
                for (int d = 0; d < 3; d++) {
                    int col = tx + d - 1;
                    v[r][d] = (col >= 0 && col < 64) ? strip[c * 384 + r * 64 + col] : 0.f;
                }
            const float* Ac = &Aall[(cg * 8 + c) * 384];
#pragma unroll
            for (int i = 0; i < 8; i++) {
                int m = ty + 4 * i;
                float4 w0 = *(const float4*)(Ac + m * 12);
                float4 w1v = *(const float4*)(Ac + m * 12 + 4);
                float w8 = Ac[m * 12 + 8];
                float wk[9] = {w0.x, w0.y, w0.z, w0.w, w1v.x, w1v.y, w1v.z, w1v.w, w8};
#pragma unroll
                for (int kk = 0; kk < 9; kk++) {
                    int dy = kk / 3, dx = kk % 3;
#pragma unroll
                    for (int j = 0; j < 4; j++)
                        acc[i][j] += wk[kk] * v[j + dy][dx];
                }
            }
        }
    }
#pragma unroll
    for (int i = 0; i < 8; i++) {
        int m = ty + 4 * i;
        if (m < 27) {
#pragma unroll
            for (int j = 0; j < 4; j++) {
                int p = ((y0 + j) << 6) + tx;
                atomicAdd(&om[((size_t)b * 27 + m) * PP + p], acc[i][j]);
            }
        }
    }
}

// ---------------------------------------------------------------------------
// w2 fp32 [o][c][tap] -> bf16, K reordered: w2bf[o][tap*256 + c]
// ---------------------------------------------------------------------------
__global__ __launch_bounds__(256)
void w2conv(const float* __restrict__ w2, unsigned short* __restrict__ w2bf) {
    int t = blockIdx.x * 256 + threadIdx.x;
    if (t >= 256 * 2304) return;
    int o = t / 2304;
    int r = t - o * 2304;
    int tap = r >> 8, c = r & 255;
    w2bf[t] = f2bf(w2[((size_t)o * 256 + c) * 9 + tap]);
}

// ---------------------------------------------------------------------------
// Deformable einsum, bf16 MFMA. R16: pixel tile 32 -> 64 (grid 256 blocks,
// 1/CU). R15 post-mortem: prefetch was NULL; accounting shows the kernel is
// memory-pipe-THROUGHPUT bound: ~55k cy/CU of L2 line requests (A-staging =
// 64 distinct 64B lines/wave/segment since each lane's 64B row-slice is its
// own line; corners 32) + ~58k cy LDS of the 176k cy runtime. A-traffic per
// output pixel is the knob: doubling the N-tile halves A lines AND LDS
// bytes per output. Corners become uint4 (8 contiguous ch per corner, same
// line count/wave as A). 16 MFMA/wave/segment (acc[2][4]). Prefetch kept;
// both full barriers kept (proven).
// ---------------------------------------------------------------------------
__global__ __launch_bounds__(512, 2)
void gemm2_mfma(const unsigned short* __restrict__ bfAT,
                const unsigned short* __restrict__ w2bf,
                const float* __restrict__ om, float* __restrict__ out2) {
    const int blk = blockIdx.x;        // 256 blocks
    const int xcd = blk & 7;
    const int b = xcd >> 1;                          // batch per XCD-pair
    const int p0 = (((blk >> 3) << 1) | (xcd & 1)) * 64;
    const int tid = threadIdx.x;
    const int lane = tid & 63;
    const int wid = tid >> 6;          // 0..7
    const int l15 = lane & 15;
    const int quad = lane >> 4;        // 0..3

    __shared__ __align__(16) unsigned short As0[256 * 40];   // 20 KB
    __shared__ __align__(16) unsigned short As1[256 * 40];   // 20 KB
    __shared__ __align__(16) unsigned short Bs0[64 * 40];    // 5 KB
    __shared__ __align__(16) unsigned short Bs1[64 * 40];    // 5 KB
    __shared__ float sw0[576], sw1[576], sw2[576], sw3[576]; // SoA tables
    __shared__ int   si0[576], si1[576];                     // row indices

    // sampling tables, 9 taps x 64 pixels
    const float* ob = om + (size_t)b * 27 * PP;
    for (int e = tid; e < 576; e += 512) {
        int k = e >> 6, p = e & 63;
        int pg = p0 + p;
        float offx = ob[(size_t)k * PP + pg];
        float offy = ob[(size_t)(9 + k) * PP + pg];
        float ms = 1.f / (1.f + expf(-ob[(size_t)(18 + k) * PP + pg]));
        int y = pg >> 6, x = pg & 63;
        float py = (float)(y + k / 3 - 1) + offy;
        float px = (float)(x + (k % 3) - 1) + offx;
        float y0f = floorf(py), x0f = floorf(px);
        float wy1 = py - y0f, wx1 = px - x0f;
        int iy0 = (int)y0f, ix0 = (int)x0f;
        int iy1 = iy0 + 1;
        float wy0v = (iy0 >= 0 && iy0 < 64) ? (1.f - wy1) * ms : 0.f;
        float wy1v = (iy1 >= 0 && iy1 < 64) ? wy1 * ms : 0.f;
        int cy0 = min(max(iy0, 0), 63), cy1 = min(max(iy1, 0), 63);
        float xa, xb; int q;
        if (ix0 >= 0 && ix0 <= 62)      { q = ix0; xa = 1.f - wx1; xb = wx1;       }
        else if (ix0 == -1)             { q = 0;   xa = wx1;       xb = 0.f;       }
        else if (ix0 == 63)             { q = 62;  xa = 0.f;       xb = 1.f - wx1; }
        else                            { q = 0;   xa = 0.f;       xb = 0.f;       }
        sw0[e] = wy0v * xa;
        sw1[e] = wy0v * xb;
        sw2[e] = wy1v * xa;
        sw3[e] = wy1v * xb;
        si0[e] = (cy0 << 6) + q;
        si1[e] = (cy1 << 6) + q;
    }

    floatx4 acc[2][4];
#pragma unroll
    for (int i = 0; i < 2; i++)
#pragma unroll
        for (int j = 0; j < 4; j++) acc[i][j] = (floatx4){0.f, 0.f, 0.f, 0.f};

    const int cq = tid & 7;            // channel octet (8 contiguous channels)
    const int bp = tid >> 3;           // pixel within tile 0..63
    const int so = tid >> 1;           // A-stage row 0..255
    const int sh = tid & 1;            // A-stage half (which 32-ch slice)
    const unsigned short* xbase = bfAT + (((size_t)b) << 20);   // b*PP*256
    const unsigned short* abase = w2bf + (size_t)so * 2304 + sh * 32;
    const unsigned short* gbq = xbase + cq * 8;
    const int mbase = wid * 32;

    __syncthreads();   // tables ready

    // ---- prologue: issue loads for segment 0 (cc2=0, tap=0) ----
    float4 a0, a1, a2, a3;
    uint4 v00, v01, v10, v11;
    float w0, w1, w2v, w3v;
    {
        a0 = ((const float4*)abase)[0];
        a1 = ((const float4*)abase)[1];
        a2 = ((const float4*)abase)[2];
        a3 = ((const float4*)abase)[3];
        int tix = bp;
        w0 = sw0[tix]; w1 = sw1[tix]; w2v = sw2[tix]; w3v = sw3[tix];
        int r0 = si0[tix], r1 = si1[tix];
        v00 = *(const uint4*)(gbq + ((size_t)r0 << 8));
        v01 = *(const uint4*)(gbq + ((size_t)(r0 + 1) << 8));
        v10 = *(const uint4*)(gbq + ((size_t)r1 << 8));
        v11 = *(const uint4*)(gbq + ((size_t)(r1 + 1) << 8));
    }

    int tap = 0, cc2 = 0;
    for (int seg = 0; seg < 36; ++seg) {
        // ---- interp current (regs loaded one segment ago) + stage ----
        float f0 = w0 * bflo(v00.x) + w1 * bflo(v01.x)
                 + w2v * bflo(v10.x) + w3v * bflo(v11.x);
        float f1 = w0 * bfhi(v00.x) + w1 * bfhi(v01.x)
                 + w2v * bfhi(v10.x) + w3v * bfhi(v11.x);
        float f2 = w0 * bflo(v00.y) + w1 * bflo(v01.y)
                 + w2v * bflo(v10.y) + w3v * bflo(v11.y);
        float f3 = w0 * bfhi(v00.y) + w1 * bfhi(v01.y)
                 + w2v * bfhi(v10.y) + w3v * bfhi(v11.y);
        float f4 = w0 * bflo(v00.z) + w1 * bflo(v01.z)
                 + w2v * bflo(v10.z) + w3v * bflo(v11.z);
        float f5 = w0 * bfhi(v00.z) + w1 * bfhi(v01.z)
                 + w2v * bfhi(v10.z) + w3v * bfhi(v11.z);
        float f6 = w0 * bflo(v00.w) + w1 * bflo(v01.w)
                 + w2v * bflo(v10.w) + w3v * bflo(v11.w);
        float f7 = w0 * bfhi(v00.w) + w1 * bfhi(v01.w)
                 + w2v * bfhi(v10.w) + w3v * bfhi(v11.w);
        uint4 bw;
        bw.x = (unsigned int)f2bf(f0) | ((unsigned int)f2bf(f1) << 16);
        bw.y = (unsigned int)f2bf(f2) | ((unsigned int)f2bf(f3) << 16);
        bw.z = (unsigned int)f2bf(f4) | ((unsigned int)f2bf(f5) << 16);
        bw.w = (unsigned int)f2bf(f6) | ((unsigned int)f2bf(f7) << 16);
        unsigned short* adst = sh ? As1 : As0;
        *(float4*)((char*)adst + so * 80 +  0) = a0;
        *(float4*)((char*)adst + so * 80 + 16) = a1;
        *(float4*)((char*)adst + so * 80 + 32) = a2;
        *(float4*)((char*)adst + so * 80 + 48) = a3;
        unsigned short* bdst = (cq & 4) ? Bs1 : Bs0;
        *(uint4*)((char*)bdst + bp * 80 + (cq & 3) * 16) = bw;
        __syncthreads();

        // ---- issue next segment's loads (hide under MFMA + barrier) ----
        int ntap = tap + 1, ncc2 = cc2;
        if (ntap == 9) { ntap = 0; ncc2 = (cc2 + 1) & 3; }
        {
            const unsigned short* gsrc = abase + ntap * 256 + ncc2 * 64;
            a0 = ((const float4*)gsrc)[0];
            a1 = ((const float4*)gsrc)[1];
            a2 = ((const float4*)gsrc)[2];
            a3 = ((const float4*)gsrc)[3];
            int tix = ntap * 64 + bp;
            int r0 = si0[tix], r1 = si1[tix];
            const unsigned short* gb = gbq + ncc2 * 64;
            v00 = *(const uint4*)(gb + ((size_t)r0 << 8));
            v01 = *(const uint4*)(gb + ((size_t)(r0 + 1) << 8));
            v10 = *(const uint4*)(gb + ((size_t)r1 << 8));
            v11 = *(const uint4*)(gb + ((size_t)(r1 + 1) << 8));
            w0 = sw0[tix]; w1 = sw1[tix]; w2v = sw2[tix]; w3v = sw3[tix];
        }

        // ---- MFMA on current LDS ----
        shortx8 af[2][2], bfr[2][4];
#pragma unroll
        for (int i = 0; i < 2; i++) {
            af[0][i] = *(const shortx8*)((const char*)As0 +
                       (mbase + 16 * i + l15) * 80 + quad * 16);
            af[1][i] = *(const shortx8*)((const char*)As1 +
                       (mbase + 16 * i + l15) * 80 + quad * 16);
        }
#pragma unroll
        for (int j = 0; j < 4; j++) {
            bfr[0][j] = *(const shortx8*)((const char*)Bs0 +
                        (16 * j + l15) * 80 + quad * 16);
            bfr[1][j] = *(const shortx8*)((const char*)Bs1 +
                        (16 * j + l15) * 80 + quad * 16);
        }
#pragma unroll
        for (int ks = 0; ks < 2; ks++)
#pragma unroll
            for (int i = 0; i < 2; i++)
#pragma unroll
                for (int j = 0; j < 4; j++)
                    acc[i][j] = __builtin_amdgcn_mfma_f32_16x16x32_bf16(
                        af[ks][i], bfr[ks][j], acc[i][j], 0, 0, 0);
        __syncthreads();
        tap = ntap; cc2 = ncc2;
    }

    // epilogue: D col = lane&15 (pixel), row = quad*4+reg
    const size_t chbase = ((size_t)b * CB) << 12;
#pragma unroll
    for (int i = 0; i < 2; i++) {
#pragma unroll
        for (int r = 0; r < 4; r++) {
            int row = mbase + 16 * i + quad * 4 + r;
            float* dst = out2 + chbase + ((size_t)row << 12) + p0 + l15;
#pragma unroll
            for (int j = 0; j < 4; j++)
                dst[16 * j] = acc[i][j][r];
        }
    }
}

// ---------------------------------------------------------------------------
// Final: relu(gn3(d_out)*sc+bi + x) in place.
// ---------------------------------------------------------------------------
__global__ __launch_bounds__(256)
void final_k(float* __restrict__ dout, const float* __restrict__ x,
             const float2* __restrict__ stats, const float* __restrict__ sc,
             const float* __restrict__ bi) {
    long i = (long)blockIdx.x * 256 + threadIdx.x;
    long total4 = ((long)BATCH * CIN * PP) >> 2;
    if (i >= total4) return;
    long e = i << 2;
    int c = (int)((e >> 12) & 1023);
    int b = (int)(e >> 22);
    float2 st = stats[b * 32 + (c >> 5)];
    float a = st.y * sc[c];
    float bb = bi[c] - st.x * a;
    float4 v = ((float4*)dout)[i];
    float4 xv = ((const float4*)x)[i];
    v.x = fmaxf(v.x * a + bb + xv.x, 0.f);
    v.y = fmaxf(v.y * a + bb + xv.y, 0.f);
    v.z = fmaxf(v.z * a + bb + xv.z, 0.f);
    v.w = fmaxf(v.w * a + bb + xv.w, 0.f);
    ((float4*)dout)[i] = v;
}

// ---------------------------------------------------------------------------
// Workspace layout: bfAT at ws+6422528 (pixel-major GN1 out); part buffer
// after st3.
// ---------------------------------------------------------------------------
extern "C" void kernel_launch(void* const* d_in, const int* in_sizes, int n_in,
                              void* d_out, int out_size, void* d_ws, size_t ws_size,
                              hipStream_t stream) {
    const float* x   = (const float*)d_in[0];
    const float* w1  = (const float*)d_in[1];
    const float* g1s = (const float*)d_in[2];
    const float* g1b = (const float*)d_in[3];
    const float* wof = (const float*)d_in[4];
    const float* bof = (const float*)d_in[5];
    const float* w2  = (const float*)d_in[6];
    const float* g2s = (const float*)d_in[7];
    const float* g2b = (const float*)d_in[8];
    const float* w3  = (const float*)d_in[9];
    const float* g3s = (const float*)d_in[10];
    const float* g3b = (const float*)d_in[11];
    float* out = (float*)d_out;

    float* ws = (float*)d_ws;
    unsigned short* w1bf   = (unsigned short*)(ws + 0);
    float*          out1r  = ws + 131072;               // conv1 raw out
    float*          out2   = ws + 131072;               // aliases out1r (dead)
    unsigned short* xbfT   = (unsigned short*)(ws + 4325376);
    unsigned short* bfA    = (unsigned short*)(ws + 4325376);
    unsigned short* bfAT   = (unsigned short*)(ws + 6422528);  // pixel-major GN1 out
    float*          om     = ws + 8519680;
    unsigned short* w2bf   = (unsigned short*)(ws + 8962048);
    unsigned short* out2bT = (unsigned short*)(ws + 4325376); // aliases bfA (dead)
    unsigned short* w3bf   = (unsigned short*)(ws + 11354112);
    float2* st1  = (float2*)(ws + 11485184);
    float2* st2  = st1 + 128;
    float2* st3  = st2 + 128;
    float2* part = st3 + 128;          // 512 float2 scratch for split stats

    // x [b][1024][4096] -> xbfT [b][4096][1024] bf16
    transp_bf16<<<dim3(64, 16, 4), 256, 0, stream>>>(x, xbfT, 1024, 4096);
    cvt_bf16<<<1024, 256, 0, stream>>>(w1, w1bf, 262144);
    // conv1: out1r[b][256][4096] = w1bf @ xbfT   (xbfT dead after this)
    gemm_bf16<<<dim3(32, 2, 4), 256, 0, stream>>>(w1bf, xbfT, out1r, 256, 4096, 1024);
    gn_stats_part<<<512, 256, 0, stream>>>(out1r, part, 256, 8);
    gn_stats_fin<<<1, 128, 0, stream>>>(part, st1, 8 * PP);
    // GN1 apply -> bfA (channel-major) + bfAT (pixel-major) in one pass
    gn1_dual<<<dim3(64, 4, 4), 256, 0, stream>>>(out1r, st1, g1s, g1b, bfA, bfAT);
    // offset conv (reads bfA)
    om_init<<<1728, 256, 0, stream>>>(om, bof);
    conv_off_k<<<dim3(16, 8, 4), 256, 0, stream>>>(bfA, wof, om);
    // weight conversions
    w2conv<<<2304, 256, 0, stream>>>(w2, w2bf);
    cvt_bf16<<<1024, 256, 0, stream>>>(w3, w3bf, 262144);
    // deformable einsum -> out2; 256 blocks (64-px tiles), XCD<->batch swizzle
    gemm2_mfma<<<dim3(256, 1, 1), 512, 0, stream>>>(bfAT, w2bf, om, out2);
    // GN2 stats + fused apply/relu/transpose -> out2bT (bfA region, now dead)
    gn_stats_part<<<512, 256, 0, stream>>>(out2, part, 256, 8);
    gn_stats_fin<<<1, 128, 0, stream>>>(part, st2, 8 * PP);
    gn2t<<<dim3(64, 4, 4), 256, 0, stream>>>(out2, st2, g2s, g2b, out2bT);
    // conv3: out[b][1024][4096] = w3bf @ out2bT
    gemm_bf16<<<dim3(32, 8, 4), 256, 0, stream>>>(w3bf, out2bT, out, 1024, 4096, 256);
    gn_stats_part<<<512, 256, 0, stream>>>(out, part, 1024, 32);
    gn_stats_fin<<<1, 128, 0, stream>>>(part, st3, 32 * PP);
    final_k<<<16384, 256, 0, stream>>>(out, x, st3, g3s, g3b);
}

// Round 7
// 348.751 us; speedup vs baseline: 1.5330x; 1.1079x over previous
//
#include <hip/hip_runtime.h>
#include <math.h>

#define BATCH 4
#define CIN   1024
#define CB    256
#define HH    64
#define WW    64
#define PP    4096          // HH*WW
#define EPSV  1e-5f

using shortx8 = __attribute__((ext_vector_type(8))) short;
using floatx4 = __attribute__((ext_vector_type(4))) float;
using intx4   = __attribute__((ext_vector_type(4))) int;

static __device__ inline unsigned short f2bf(float f) {
    unsigned int u = __float_as_uint(f);
    u += 0x7fffu + ((u >> 16) & 1u);      // RNE
    return (unsigned short)(u >> 16);
}
static __device__ inline float bf2f(unsigned short s) {
    return __uint_as_float(((unsigned int)s) << 16);
}
static __device__ inline float bflo(unsigned int u) {
    return __uint_as_float(u << 16);
}
static __device__ inline float bfhi(unsigned int u) {
    return __uint_as_float(u & 0xffff0000u);
}

// ---------------------------------------------------------------------------
// bf16 MFMA GEMM (conv1 / conv3). Unchanged from R4 (proven).
// ---------------------------------------------------------------------------
__global__ __launch_bounds__(256)
void gemm_bf16(const unsigned short* __restrict__ A,
               const unsigned short* __restrict__ BTg,
               float* __restrict__ Cg, int M, int N, int K) {
    const int b = blockIdx.z;
    const unsigned short* BT = BTg + (size_t)b * N * K;
    float* C = Cg + (size_t)b * M * N;
    const int m0 = blockIdx.y * 128;
    const int n0 = blockIdx.x * 128;
    const int tid = threadIdx.x;
    const int lane = tid & 63;
    const int wid = tid >> 6;
    const int l15 = lane & 15;
    const int quad = lane >> 4;

    __shared__ __align__(16) unsigned short As[128 * 40];
    __shared__ __align__(16) unsigned short Bs[128 * 40];

    floatx4 acc[2][8];
#pragma unroll
    for (int i = 0; i < 2; i++)
#pragma unroll
        for (int j = 0; j < 8; j++) acc[i][j] = (floatx4){0.f, 0.f, 0.f, 0.f};

    const int row = tid >> 1;
    const int half = tid & 1;

    for (int k0 = 0; k0 < K; k0 += 32) {
        const unsigned short* ga = A + (size_t)(m0 + row) * K + k0 + half * 16;
        const unsigned short* gb = BT + (size_t)(n0 + row) * K + k0 + half * 16;
        float4 a0 = *(const float4*)ga;
        float4 a1 = *(const float4*)(ga + 8);
        float4 b0 = *(const float4*)gb;
        float4 b1 = *(const float4*)(gb + 8);
        __syncthreads();
        *(float4*)((char*)As + row * 80 + half * 32) = a0;
        *(float4*)((char*)As + row * 80 + half * 32 + 16) = a1;
        *(float4*)((char*)Bs + row * 80 + half * 32) = b0;
        *(float4*)((char*)Bs + row * 80 + half * 32 + 16) = b1;
        __syncthreads();
        shortx8 af[2], bf[8];
#pragma unroll
        for (int i = 0; i < 2; i++)
            af[i] = *(const shortx8*)((const char*)As +
                    (wid * 32 + 16 * i + l15) * 80 + quad * 16);
#pragma unroll
        for (int j = 0; j < 8; j++)
            bf[j] = *(const shortx8*)((const char*)Bs +
                    (16 * j + l15) * 80 + quad * 16);
#pragma unroll
        for (int i = 0; i < 2; i++)
#pragma unroll
            for (int j = 0; j < 8; j++)
                acc[i][j] = __builtin_amdgcn_mfma_f32_16x16x32_bf16(
                    af[i], bf[j], acc[i][j], 0, 0, 0);
    }

#pragma unroll
    for (int i = 0; i < 2; i++) {
#pragma unroll
        for (int r = 0; r < 4; r++) {
            int m = m0 + wid * 32 + 16 * i + quad * 4 + r;
            float* dst = C + (size_t)m * N + n0 + l15;
#pragma unroll
            for (int j = 0; j < 8; j++)
                dst[16 * j] = acc[i][j][r];
        }
    }
}

// ---------------------------------------------------------------------------
// Tiled transpose + fp32->bf16: src [b][C][P] -> dst [b][P][C]
// ---------------------------------------------------------------------------
__global__ __launch_bounds__(256)
void transp_bf16(const float* __restrict__ src, unsigned short* __restrict__ dst,
                 int C, int P) {
    const int p0 = blockIdx.x * 64;
    const int c0 = blockIdx.y * 64;
    const int b = blockIdx.z;
    __shared__ unsigned short t[64][72];
    const float* s = src + ((size_t)b * C + c0) * P + p0;
    for (int e = threadIdx.x; e < 4096; e += 256) {
        int r = e >> 6, col = e & 63;
        t[r][col] = f2bf(s[(size_t)r * P + col]);
    }
    __syncthreads();
    unsigned short* d = dst + ((size_t)b * P + p0) * C + c0;
    for (int u = threadIdx.x; u < 512; u += 256) {
        int pr = u >> 3, c8 = (u & 7) * 8;
        ushort4 v0, v1;
        v0.x = t[c8 + 0][pr]; v0.y = t[c8 + 1][pr];
        v0.z = t[c8 + 2][pr]; v0.w = t[c8 + 3][pr];
        v1.x = t[c8 + 4][pr]; v1.y = t[c8 + 5][pr];
        v1.z = t[c8 + 6][pr]; v1.w = t[c8 + 7][pr];
        *(ushort4*)&d[(size_t)pr * C + c8] = v0;
        *(ushort4*)&d[(size_t)pr * C + c8 + 4] = v1;
    }
}

// ---------------------------------------------------------------------------
// GN apply + ReLU + transpose-convert: src fp32 [b][256][P] -> bf16 [b][P][256]
// (used for gn1 -> bfAT and gn2 -> out2bT)
// ---------------------------------------------------------------------------
__global__ __launch_bounds__(256)
void gn2t(const float* __restrict__ src, const float2* __restrict__ st,
          const float* __restrict__ sc, const float* __restrict__ bi,
          unsigned short* __restrict__ dst) {
    const int p0 = blockIdx.x * 64;
    const int c0 = blockIdx.y * 64;
    const int b = blockIdx.z;
    __shared__ unsigned short t[64][72];
    const float* s = src + ((size_t)b * CB + c0) * PP + p0;
    for (int e = threadIdx.x; e < 4096; e += 256) {
        int r = e >> 6, col = e & 63;
        int c = c0 + r;
        float2 m = st[b * 32 + (c >> 3)];       // Cpg = 8
        float a = m.y * sc[c];
        float bb = bi[c] - m.x * a;
        t[r][col] = f2bf(fmaxf(s[(size_t)r * PP + col] * a + bb, 0.f));
    }
    __syncthreads();
    unsigned short* d = dst + ((size_t)b * PP + p0) * CB + c0;
    for (int u = threadIdx.x; u < 512; u += 256) {
        int pr = u >> 3, c8 = (u & 7) * 8;
        ushort4 v0, v1;
        v0.x = t[c8 + 0][pr]; v0.y = t[c8 + 1][pr];
        v0.z = t[c8 + 2][pr]; v0.w = t[c8 + 3][pr];
        v1.x = t[c8 + 4][pr]; v1.y = t[c8 + 5][pr];
        v1.z = t[c8 + 6][pr]; v1.w = t[c8 + 7][pr];
        *(ushort4*)&d[(size_t)pr * CB + c8] = v0;
        *(ushort4*)&d[(size_t)pr * CB + c8 + 4] = v1;
    }
}

// ---------------------------------------------------------------------------
__global__ __launch_bounds__(256)
void cvt_bf16(const float* __restrict__ s, unsigned short* __restrict__ d, int n) {
    int i = blockIdx.x * 256 + threadIdx.x;
    if (i < n) d[i] = f2bf(s[i]);
}

// ---------------------------------------------------------------------------
// GN stats, split 4-way per (b,group): 512 blocks. Partial + finalize.
// ---------------------------------------------------------------------------
__global__ __launch_bounds__(256)
void gn_stats_part(const float* __restrict__ src, float2* __restrict__ part,
                   int C, int Cpg) {
    int bgs = blockIdx.x;
    int bg = bgs >> 2, s = bgs & 3;
    int b = bg >> 5, g = bg & 31;
    const float* base = src + ((size_t)b * C + (size_t)g * Cpg) * PP;
    int n4 = (Cpg * PP) >> 2;
    int per = n4 >> 2;
    const float4* p4 = (const float4*)base + (size_t)s * per;
    float sm = 0.f, ss = 0.f;
    for (int i = threadIdx.x; i < per; i += 256) {
        float4 v = p4[i];
        sm += v.x + v.y + v.z + v.w;
        ss += v.x * v.x + v.y * v.y + v.z * v.z + v.w * v.w;
    }
    for (int off = 32; off > 0; off >>= 1) {
        sm += __shfl_down(sm, off, 64);
        ss += __shfl_down(ss, off, 64);
    }
    __shared__ float rs[4], rss[4];
    int lane = threadIdx.x & 63, wid = threadIdx.x >> 6;
    if (lane == 0) { rs[wid] = sm; rss[wid] = ss; }
    __syncthreads();
    if (threadIdx.x == 0)
        part[bgs] = make_float2(rs[0] + rs[1] + rs[2] + rs[3],
                                rss[0] + rss[1] + rss[2] + rss[3]);
}

__global__ __launch_bounds__(128)
void gn_stats_fin(const float2* __restrict__ part, float2* __restrict__ stats,
                  int cnt) {
    int bg = threadIdx.x;           // 128 (b,g) pairs
    float2 p0 = part[bg * 4 + 0], p1 = part[bg * 4 + 1];
    float2 p2 = part[bg * 4 + 2], p3 = part[bg * 4 + 3];
    float S  = p0.x + p1.x + p2.x + p3.x;
    float SS = p0.y + p1.y + p2.y + p3.y;
    float mean = S / (float)cnt;
    float var = SS / (float)cnt - mean * mean;
    stats[bg] = make_float2(mean, rsqrtf(var + EPSV));
}

// ---------------------------------------------------------------------------
// w_off fp32 [27][256][9] -> bf16 wobf [32][2304], layout m*2304 + tap*256 + c,
// rows 27..31 zero (M padded to 32 for MFMA).
// ---------------------------------------------------------------------------
__global__ __launch_bounds__(256)
void woff_conv(const float* __restrict__ w_off, unsigned short* __restrict__ wobf) {
    int t = blockIdx.x * 256 + threadIdx.x;
    if (t >= 32 * 2304) return;
    int m = t / 2304;
    int r = t - m * 2304;
    int tap = r >> 8, c = r & 255;
    float v = (m < 27) ? w_off[((size_t)m * 256 + c) * 9 + tap] : 0.f;
    wobf[t] = f2bf(v);
}

// ---------------------------------------------------------------------------
// R17: offset conv on MFMA. om[b][27][4096] = W[27][2304] @ im2col + b_off.
// Old conv_off_k: 68 us, MfmaUtil 0, VALUBusy 38% — a 2.0 GFLOP GEMM on the
// VALU (floor ~20 us at 103 TF) at 18.7% occupancy. bfAT (pixel-major) makes
// the im2col column for regular tap (dy,dx) a CONTIGUOUS 512B row slice:
// structurally identical to gemm2. Per tap: stage shifted 32px x 256ch
// B-tile in LDS (16 lines/wave, coalesced), A-frags direct from L2-resident
// wobf (16 lines/frag, exact MFMA lane layout), 8 MFMA/wave. 512 blocks
// (2/CU) x 4 waves in 16x16 quadrants. Bias in epilogue: om_init + atomicAdd
// die; bfA (channel-major) becomes fully dead.
// LDS: 8 cc-chunks x [32px x 80B] (proven 2-way-max pattern), cc stride
// 2576B (=/=0 mod 128 to spread stage-write banks). 20.6 KB total.
// ---------------------------------------------------------------------------
__global__ __launch_bounds__(256)
void conv_off_mfma(const unsigned short* __restrict__ bfAT,
                   const unsigned short* __restrict__ wobf,
                   const float* __restrict__ boff,
                   float* __restrict__ om) {
    const int blk = blockIdx.x;          // 512 blocks
    const int xcd = blk & 7;
    const int b = xcd >> 1;              // batch per XCD-pair
    const int tile = ((blk >> 3) << 1) | (xcd & 1);   // 0..127
    const int p0 = tile * 32;
    const int tid = threadIdx.x;
    const int lane = tid & 63;
    const int wid = tid >> 6;            // 0..3
    const int l15 = lane & 15;
    const int quad = lane >> 4;
    const int mh = (wid >> 1) << 4;      // m-half: 0 or 16
    const int ph = (wid & 1) << 4;       // px-half: 0 or 16

    __shared__ __align__(16) unsigned short Bs[8 * 1288];   // 20.6 KB

    const int y0r = p0 >> 6;             // image row (constant per tile)
    const int x0 = p0 & 63;              // 0 or 32
    const unsigned short* xb = bfAT + ((size_t)b << 20);
    const unsigned short* arow = wobf + (size_t)(mh + l15) * 2304 + quad * 8;

    floatx4 acc = (floatx4){0.f, 0.f, 0.f, 0.f};

    for (int tap = 0; tap < 9; ++tap) {
        const int dy = tap / 3 - 1, dx = tap % 3 - 1;
        const int yy = y0r + dy;
        const bool rowok = (yy >= 0 && yy < 64);
        __syncthreads();
        for (int e = tid; e < 1024; e += 256) {
            int px = e >> 5, ck = e & 31;
            int xx = x0 + px + dx;
            uint4 v = make_uint4(0u, 0u, 0u, 0u);
            if (rowok && xx >= 0 && xx < 64) {
                int srow = (yy << 6) + xx;
                v = *(const uint4*)(xb + ((size_t)srow << 8) + ck * 8);
            }
            *(uint4*)((char*)Bs + (ck >> 2) * 2576 + px * 80 + (ck & 3) * 16) = v;
        }
        __syncthreads();
        const unsigned short* at = arow + tap * 256;
#pragma unroll
        for (int cc = 0; cc < 8; ++cc) {
            shortx8 af = *(const shortx8*)(at + cc * 32);
            shortx8 bf = *(const shortx8*)((const char*)Bs + cc * 2576 +
                         (ph + l15) * 80 + quad * 16);
            acc = __builtin_amdgcn_mfma_f32_16x16x32_bf16(af, bf, acc, 0, 0, 0);
        }
    }

    // epilogue: col = l15 (pixel), row = quad*4 + r (within m-half); + bias
#pragma unroll
    for (int r = 0; r < 4; ++r) {
        int m = mh + quad * 4 + r;
        if (m < 27)
            om[((size_t)b * 27 + m) * PP + p0 + ph + l15] = acc[r] + boff[m];
    }
}

// ---------------------------------------------------------------------------
// Deformable einsum, bf16 MFMA. R16 version (proven): 64-px tiles, 256
// blocks, coalesced pixel-major gathers, depth-1 register prefetch.
// ---------------------------------------------------------------------------
__global__ __launch_bounds__(512, 2)
void gemm2_mfma(const unsigned short* __restrict__ bfAT,
                const unsigned short* __restrict__ w2bf,
                const float* __restrict__ om, float* __restrict__ out2) {
    const int blk = blockIdx.x;        // 256 blocks
    const int xcd = blk & 7;
    const int b = xcd >> 1;                          // batch per XCD-pair
    const int p0 = (((blk >> 3) << 1) | (xcd & 1)) * 64;
    const int tid = threadIdx.x;
    const int lane = tid & 63;
    const int wid = tid >> 6;          // 0..7
    const int l15 = lane & 15;
    const int quad = lane >> 4;        // 0..3

    __shared__ __align__(16) unsigned short As0[256 * 40];   // 20 KB
    __shared__ __align__(16) unsigned short As1[256 * 40];   // 20 KB
    __shared__ __align__(16) unsigned short Bs0[64 * 40];    // 5 KB
    __shared__ __align__(16) unsigned short Bs1[64 * 40];    // 5 KB
    __shared__ float sw0[576], sw1[576], sw2[576], sw3[576]; // SoA tables
    __shared__ int   si0[576], si1[576];                     // row indices

    // sampling tables, 9 taps x 64 pixels
    const float* ob = om + (size_t)b * 27 * PP;
    for (int e = tid; e < 576; e += 512) {
        int k = e >> 6, p = e & 63;
        int pg = p0 + p;
        float offx = ob[(size_t)k * PP + pg];
        float offy = ob[(size_t)(9 + k) * PP + pg];
        float ms = 1.f / (1.f + expf(-ob[(size_t)(18 + k) * PP + pg]));
        int y = pg >> 6, x = pg & 63;
        float py = (float)(y + k / 3 - 1) + offy;
        float px = (float)(x + (k % 3) - 1) + offx;
        float y0f = floorf(py), x0f = floorf(px);
        float wy1 = py - y0f, wx1 = px - x0f;
        int iy0 = (int)y0f, ix0 = (int)x0f;
        int iy1 = iy0 + 1;
        float wy0v = (iy0 >= 0 && iy0 < 64) ? (1.f - wy1) * ms : 0.f;
        float wy1v = (iy1 >= 0 && iy1 < 64) ? wy1 * ms : 0.f;
        int cy0 = min(max(iy0, 0), 63), cy1 = min(max(iy1, 0), 63);
        float xa, xb; int q;
        if (ix0 >= 0 && ix0 <= 62)      { q = ix0; xa = 1.f - wx1; xb = wx1;       }
        else if (ix0 == -1)             { q = 0;   xa = wx1;       xb = 0.f;       }
        else if (ix0 == 63)             { q = 62;  xa = 0.f;       xb = 1.f - wx1; }
        else                            { q = 0;   xa = 0.f;       xb = 0.f;       }
        sw0[e] = wy0v * xa;
        sw1[e] = wy0v * xb;
        sw2[e] = wy1v * xa;
        sw3[e] = wy1v * xb;
        si0[e] = (cy0 << 6) + q;
        si1[e] = (cy1 << 6) + q;
    }

    floatx4 acc[2][4];
#pragma unroll
    for (int i = 0; i < 2; i++)
#pragma unroll
        for (int j = 0; j < 4; j++) acc[i][j] = (floatx4){0.f, 0.f, 0.f, 0.f};

    const int cq = tid & 7;            // channel octet (8 contiguous channels)
    const int bp = tid >> 3;           // pixel within tile 0..63
    const int so = tid >> 1;           // A-stage row 0..255
    const int sh = tid & 1;            // A-stage half (which 32-ch slice)
    const unsigned short* xbase = bfAT + (((size_t)b) << 20);   // b*PP*256
    const unsigned short* abase = w2bf + (size_t)so * 2304 + sh * 32;
    const unsigned short* gbq = xbase + cq * 8;
    const int mbase = wid * 32;

    __syncthreads();   // tables ready

    // ---- prologue: issue loads for segment 0 (cc2=0, tap=0) ----
    float4 a0, a1, a2, a3;
    uint4 v00, v01, v10, v11;
    float w0, w1, w2v, w3v;
    {
        a0 = ((const float4*)abase)[0];
        a1 = ((const float4*)abase)[1];
        a2 = ((const float4*)abase)[2];
        a3 = ((const float4*)abase)[3];
        int tix = bp;
        w0 = sw0[tix]; w1 = sw1[tix]; w2v = sw2[tix]; w3v = sw3[tix];
        int r0 = si0[tix], r1 = si1[tix];
        v00 = *(const uint4*)(gbq + ((size_t)r0 << 8));
        v01 = *(const uint4*)(gbq + ((size_t)(r0 + 1) << 8));
        v10 = *(const uint4*)(gbq + ((size_t)r1 << 8));
        v11 = *(const uint4*)(gbq + ((size_t)(r1 + 1) << 8));
    }

    int tap = 0, cc2 = 0;
    for (int seg = 0; seg < 36; ++seg) {
        // ---- interp current (regs loaded one segment ago) + stage ----
        float f0 = w0 * bflo(v00.x) + w1 * bflo(v01.x)
                 + w2v * bflo(v10.x) + w3v * bflo(v11.x);
        float f1 = w0 * bfhi(v00.x) + w1 * bfhi(v01.x)
                 + w2v * bfhi(v10.x) + w3v * bfhi(v11.x);
        float f2 = w0 * bflo(v00.y) + w1 * bflo(v01.y)
                 + w2v * bflo(v10.y) + w3v * bflo(v11.y);
        float f3 = w0 * bfhi(v00.y) + w1 * bfhi(v01.y)
                 + w2v * bfhi(v10.y) + w3v * bfhi(v11.y);
        float f4 = w0 * bflo(v00.z) + w1 * bflo(v01.z)
                 + w2v * bflo(v10.z) + w3v * bflo(v11.z);
        float f5 = w0 * bfhi(v00.z) + w1 * bfhi(v01.z)
                 + w2v * bfhi(v10.z) + w3v * bfhi(v11.z);
        float f6 = w0 * bflo(v00.w) + w1 * bflo(v01.w)
                 + w2v * bflo(v10.w) + w3v * bflo(v11.w);
        float f7 = w0 * bfhi(v00.w) + w1 * bfhi(v01.w)
                 + w2v * bfhi(v10.w) + w3v * bfhi(v11.w);
        uint4 bw;
        bw.x = (unsigned int)f2bf(f0) | ((unsigned int)f2bf(f1) << 16);
        bw.y = (unsigned int)f2bf(f2) | ((unsigned int)f2bf(f3) << 16);
        bw.z = (unsigned int)f2bf(f4) | ((unsigned int)f2bf(f5) << 16);
        bw.w = (unsigned int)f2bf(f6) | ((unsigned int)f2bf(f7) << 16);
        unsigned short* adst = sh ? As1 : As0;
        *(float4*)((char*)adst + so * 80 +  0) = a0;
        *(float4*)((char*)adst + so * 80 + 16) = a1;
        *(float4*)((char*)adst + so * 80 + 32) = a2;
        *(float4*)((char*)adst + so * 80 + 48) = a3;
        unsigned short* bdst = (cq & 4) ? Bs1 : Bs0;
        *(uint4*)((char*)bdst + bp * 80 + (cq & 3) * 16) = bw;
        __syncthreads();

        // ---- issue next segment's loads (hide under MFMA + barrier) ----
        int ntap = tap + 1, ncc2 = cc2;
        if (ntap == 9) { ntap = 0; ncc2 = (cc2 + 1) & 3; }
        {
            const unsigned short* gsrc = abase + ntap * 256 + ncc2 * 64;
            a0 = ((const float4*)gsrc)[0];
            a1 = ((const float4*)gsrc)[1];
            a2 = ((const float4*)gsrc)[2];
            a3 = ((const float4*)gsrc)[3];
            int tix = ntap * 64 + bp;
            int r0 = si0[tix], r1 = si1[tix];
            const unsigned short* gb = gbq + ncc2 * 64;
            v00 = *(const uint4*)(gb + ((size_t)r0 << 8));
            v01 = *(const uint4*)(gb + ((size_t)(r0 + 1) << 8));
            v10 = *(const uint4*)(gb + ((size_t)r1 << 8));
            v11 = *(const uint4*)(gb + ((size_t)(r1 + 1) << 8));
            w0 = sw0[tix]; w1 = sw1[tix]; w2v = sw2[tix]; w3v = sw3[tix];
        }

        // ---- MFMA on current LDS ----
        shortx8 af[2][2], bfr[2][4];
#pragma unroll
        for (int i = 0; i < 2; i++) {
            af[0][i] = *(const shortx8*)((const char*)As0 +
                       (mbase + 16 * i + l15) * 80 + quad * 16);
            af[1][i] = *(const shortx8*)((const char*)As1 +
                       (mbase + 16 * i + l15) * 80 + quad * 16);
        }
#pragma unroll
        for (int j = 0; j < 4; j++) {
            bfr[0][j] = *(const shortx8*)((const char*)Bs0 +
                        (16 * j + l15) * 80 + quad * 16);
            bfr[1][j] = *(const shortx8*)((const char*)Bs1 +
                        (16 * j + l15) * 80 + quad * 16);
        }
#pragma unroll
        for (int ks = 0; ks < 2; ks++)
#pragma unroll
            for (int i = 0; i < 2; i++)
#pragma unroll
                for (int j = 0; j < 4; j++)
                    acc[i][j] = __builtin_amdgcn_mfma_f32_16x16x32_bf16(
                        af[ks][i], bfr[ks][j], acc[i][j], 0, 0, 0);
        __syncthreads();
        tap = ntap; cc2 = ncc2;
    }

    // epilogue: D col = lane&15 (pixel), row = quad*4+reg
    const size_t chbase = ((size_t)b * CB) << 12;
#pragma unroll
    for (int i = 0; i < 2; i++) {
#pragma unroll
        for (int r = 0; r < 4; r++) {
            int row = mbase + 16 * i + quad * 4 + r;
            float* dst = out2 + chbase + ((size_t)row << 12) + p0 + l15;
#pragma unroll
            for (int j = 0; j < 4; j++)
                dst[16 * j] = acc[i][j][r];
        }
    }
}

// ---------------------------------------------------------------------------
// w2 fp32 [o][c][tap] -> bf16, K reordered: w2bf[o][tap*256 + c]
// ---------------------------------------------------------------------------
__global__ __launch_bounds__(256)
void w2conv(const float* __restrict__ w2, unsigned short* __restrict__ w2bf) {
    int t = blockIdx.x * 256 + threadIdx.x;
    if (t >= 256 * 2304) return;
    int o = t / 2304;
    int r = t - o * 2304;
    int tap = r >> 8, c = r & 255;
    w2bf[t] = f2bf(w2[((size_t)o * 256 + c) * 9 + tap]);
}

// ---------------------------------------------------------------------------
// Final: relu(gn3(d_out)*sc+bi + x) in place.
// ---------------------------------------------------------------------------
__global__ __launch_bounds__(256)
void final_k(float* __restrict__ dout, const float* __restrict__ x,
             const float2* __restrict__ stats, const float* __restrict__ sc,
             const float* __restrict__ bi) {
    long i = (long)blockIdx.x * 256 + threadIdx.x;
    long total4 = ((long)BATCH * CIN * PP) >> 2;
    if (i >= total4) return;
    long e = i << 2;
    int c = (int)((e >> 12) & 1023);
    int b = (int)(e >> 22);
    float2 st = stats[b * 32 + (c >> 5)];
    float a = st.y * sc[c];
    float bb = bi[c] - st.x * a;
    float4 v = ((float4*)dout)[i];
    float4 xv = ((const float4*)x)[i];
    v.x = fmaxf(v.x * a + bb + xv.x, 0.f);
    v.y = fmaxf(v.y * a + bb + xv.y, 0.f);
    v.z = fmaxf(v.z * a + bb + xv.z, 0.f);
    v.w = fmaxf(v.w * a + bb + xv.w, 0.f);
    ((float4*)dout)[i] = v;
}

// ---------------------------------------------------------------------------
// Workspace layout: bfAT at ws+6422528; wobf at ws+9256960 (gap before w3bf).
// bfA region (ws+4325376) now only used as out2bT (after gemm2).
// ---------------------------------------------------------------------------
extern "C" void kernel_launch(void* const* d_in, const int* in_sizes, int n_in,
                              void* d_out, int out_size, void* d_ws, size_t ws_size,
                              hipStream_t stream) {
    const float* x   = (const float*)d_in[0];
    const float* w1  = (const float*)d_in[1];
    const float* g1s = (const float*)d_in[2];
    const float* g1b = (const float*)d_in[3];
    const float* wof = (const float*)d_in[4];
    const float* bof = (const float*)d_in[5];
    const float* w2  = (const float*)d_in[6];
    const float* g2s = (const float*)d_in[7];
    const float* g2b = (const float*)d_in[8];
    const float* w3  = (const float*)d_in[9];
    const float* g3s = (const float*)d_in[10];
    const float* g3b = (const float*)d_in[11];
    float* out = (float*)d_out;

    float* ws = (float*)d_ws;
    unsigned short* w1bf   = (unsigned short*)(ws + 0);
    float*          out1r  = ws + 131072;               // conv1 raw out
    float*          out2   = ws + 131072;               // aliases out1r (dead)
    unsigned short* xbfT   = (unsigned short*)(ws + 4325376);
    unsigned short* bfAT   = (unsigned short*)(ws + 6422528);  // pixel-major GN1 out
    float*          om     = ws + 8519680;
    unsigned short* w2bf   = (unsigned short*)(ws + 8962048);
    unsigned short* wobf   = (unsigned short*)(ws + 9256960);  // offset-conv W bf16
    unsigned short* out2bT = (unsigned short*)(ws + 4325376);  // reuses xbfT region
    unsigned short* w3bf   = (unsigned short*)(ws + 11354112);
    float2* st1  = (float2*)(ws + 11485184);
    float2* st2  = st1 + 128;
    float2* st3  = st2 + 128;
    float2* part = st3 + 128;          // 512 float2 scratch for split stats

    // x [b][1024][4096] -> xbfT [b][4096][1024] bf16
    transp_bf16<<<dim3(64, 16, 4), 256, 0, stream>>>(x, xbfT, 1024, 4096);
    cvt_bf16<<<1024, 256, 0, stream>>>(w1, w1bf, 262144);
    // conv1: out1r[b][256][4096] = w1bf @ xbfT   (xbfT dead after this)
    gemm_bf16<<<dim3(32, 2, 4), 256, 0, stream>>>(w1bf, xbfT, out1r, 256, 4096, 1024);
    gn_stats_part<<<512, 256, 0, stream>>>(out1r, part, 256, 8);
    gn_stats_fin<<<1, 128, 0, stream>>>(part, st1, 8 * PP);
    // GN1 apply + ReLU -> bfAT (pixel-major only; channel-major copy dead)
    gn2t<<<dim3(64, 4, 4), 256, 0, stream>>>(out1r, st1, g1s, g1b, bfAT);
    // offset conv on MFMA (reads bfAT; bias fused; no om_init / atomics)
    woff_conv<<<288, 256, 0, stream>>>(wof, wobf);
    conv_off_mfma<<<512, 256, 0, stream>>>(bfAT, wobf, bof, om);
    // weight conversions
    w2conv<<<2304, 256, 0, stream>>>(w2, w2bf);
    cvt_bf16<<<1024, 256, 0, stream>>>(w3, w3bf, 262144);
    // deformable einsum -> out2; 256 blocks (64-px tiles), XCD<->batch swizzle
    gemm2_mfma<<<dim3(256, 1, 1), 512, 0, stream>>>(bfAT, w2bf, om, out2);
    // GN2 stats + fused apply/relu/transpose -> out2bT
    gn_stats_part<<<512, 256, 0, stream>>>(out2, part, 256, 8);
    gn_stats_fin<<<1, 128, 0, stream>>>(part, st2, 8 * PP);
    gn2t<<<dim3(64, 4, 4), 256, 0, stream>>>(out2, st2, g2s, g2b, out2bT);
    // conv3: out[b][1024][4096] = w3bf @ out2bT
    gemm_bf16<<<dim3(32, 8, 4), 256, 0, stream>>>(w3bf, out2bT, out, 1024, 4096, 256);
    gn_stats_part<<<512, 256, 0, stream>>>(out, part, 1024, 32);
    gn_stats_fin<<<1, 128, 0, stream>>>(part, st3, 32 * PP);
    final_k<<<16384, 256, 0, stream>>>(out, x, st3, g3s, g3b);
}